// Round 7
// baseline (245.362 us; speedup 1.0000x reference)
//
#include <hip/hip_runtime.h>
#include <math.h>

#define NL 512
#define NP 1024
#define HDIM 128

#define TAB_N 8192
#define DMAX 34.65f

// ---- workspace layout (float offsets) ----
#define M_OFF    128
#define LIG_OFF  (M_OFF + NL*NP)              // lig proj 512x128
#define POC_OFF  (LIG_OFF + NL*HDIM)          // poc proj 1024x128
#define LENH_OFF (POC_OFF + NP*HDIM)          // lig_enh 512x128
#define PENH_OFF (LENH_OFF + NL*HDIM)         // poc_enh 1024x128
#define QKVL_OFF (PENH_OFF + NP*HDIM)         // qkv for lig_enh 512x384 (aliased by m(d) table earlier)
#define QKVP_OFF (QKVL_OFF + NL*384)          // qkv for poc_enh 1024x384
#define PARTL_OFF (QKVP_OFF + NP*384)         // lig partials: [512][8 h][8 slices][18]
#define PARTP_OFF (PARTL_OFF + 512*8*8*18)    // poc partials: [1024][8 h][4 slices][18]
#define TAB_OFF  QKVL_OFF                     // table consumed by agg_gate before qkv_kernel writes here

__device__ __forceinline__ float dot4f(float4 a, float4 b){
  return fmaf(a.x,b.x, fmaf(a.y,b.y, fmaf(a.z,b.z, a.w*b.w)));
}

// ---------------- proj: lig = LF@Wl.T+bl ; poc = PF@Wp.T+bp (4 rows/block) ----------------
__global__ __launch_bounds__(128) void proj_kernel(const float* __restrict__ lf, const float* __restrict__ pf,
                                                   const float* __restrict__ Wl, const float* __restrict__ bl,
                                                   const float* __restrict__ Wp, const float* __restrict__ bp,
                                                   float* __restrict__ lig, float* __restrict__ poc){
  int t = threadIdx.x;
  int row0 = blockIdx.x * 4;
  const float* in; const float* W; const float* bias; float* out;
  if (row0 < NL){ in = lf + (size_t)row0*HDIM; W = Wl; bias = bl; out = lig + (size_t)row0*HDIM; }
  else { int r = row0 - NL; in = pf + (size_t)r*HDIM; W = Wp; bias = bp; out = poc + (size_t)r*HDIM; }
  __shared__ float sin[4*HDIM];
  for (int idx = t; idx < 4*HDIM; idx += 128) sin[idx] = in[idx];
  __syncthreads();
  float bv = bias[t];
  float a0 = bv, a1 = bv, a2 = bv, a3 = bv;
  const float4* wr = (const float4*)(W + (size_t)t*HDIM);
  const float4* s0 = (const float4*)(sin);
  const float4* s1 = (const float4*)(sin + HDIM);
  const float4* s2 = (const float4*)(sin + 2*HDIM);
  const float4* s3 = (const float4*)(sin + 3*HDIM);
  #pragma unroll 8
  for (int k = 0; k < 32; k++){
    float4 w = wr[k];
    a0 = fmaf(w.x, s0[k].x, fmaf(w.y, s0[k].y, fmaf(w.z, s0[k].z, fmaf(w.w, s0[k].w, a0))));
    a1 = fmaf(w.x, s1[k].x, fmaf(w.y, s1[k].y, fmaf(w.z, s1[k].z, fmaf(w.w, s1[k].w, a1))));
    a2 = fmaf(w.x, s2[k].x, fmaf(w.y, s2[k].y, fmaf(w.z, s2[k].z, fmaf(w.w, s2[k].w, a2))));
    a3 = fmaf(w.x, s3[k].x, fmaf(w.y, s3[k].y, fmaf(w.z, s3[k].z, fmaf(w.w, s3[k].w, a3))));
  }
  out[t] = a0; out[HDIM + t] = a1; out[2*HDIM + t] = a2; out[3*HDIM + t] = a3;
}

// ---------------- table: tab[idx] = m(d_idx) via full MLP; wd3m computed inline ----------------
__global__ __launch_bounds__(256) void table_kernel(const float* __restrict__ Wd1, const float* __restrict__ bd1,
                                                    const float* __restrict__ Wd2, const float* __restrict__ bd2,
                                                    const float* __restrict__ Wd3, const float* __restrict__ bd3,
                                                    float* __restrict__ tab){
  __shared__ float sWd1[32], sbd1[32], sWd2[2048], sbd2[64], swd3m[64];
  __shared__ float sbd3m;
  int t = threadIdx.x;
  int idx = blockIdx.x * 256 + t;
  if (t < 64){
    float s = 0.f;
    #pragma unroll 8
    for (int i = 0; i < 128; i++) s += Wd3[i*64 + t];
    swd3m[t] = s * (1.f/128.f);
  } else if (t == 64){
    float s = 0.f;
    for (int i = 0; i < 128; i++) s += bd3[i];
    sbd3m = s * (1.f/128.f);
  } else if (t >= 128 && t < 160){ sWd1[t-128] = Wd1[t-128]; sbd1[t-128] = bd1[t-128]; }
  else if (t >= 160 && t < 224){ sbd2[t-160] = bd2[t-160]; }
  for (int k = t; k < 2048; k += 256) sWd2[k] = Wd2[k];
  __syncthreads();

  float d = (float)idx * (DMAX / (float)(TAB_N - 1));

  float4 e1q[8];
  const float4* w1q = (const float4*)sWd1;
  const float4* b1q = (const float4*)sbd1;
  #pragma unroll
  for (int k4 = 0; k4 < 8; k4++){
    float4 w = w1q[k4], b = b1q[k4];
    float4 e;
    e.x = fmaxf(fmaf(d, w.x, b.x), 0.f);
    e.y = fmaxf(fmaf(d, w.y, b.y), 0.f);
    e.z = fmaxf(fmaf(d, w.z, b.z), 0.f);
    e.w = fmaxf(fmaf(d, w.w, b.w), 0.f);
    e1q[k4] = e;
  }
  float mv = sbd3m;
  #pragma unroll 4
  for (int j2 = 0; j2 < 64; j2++){
    const float4* wrow = (const float4*)(sWd2 + j2*32);
    float a0 = 0.f, a1 = 0.f, a2 = 0.f, a3 = 0.f;
    #pragma unroll
    for (int k4 = 0; k4 < 8; k4++){
      float4 w = wrow[k4], e = e1q[k4];
      a0 = fmaf(w.x, e.x, a0);
      a1 = fmaf(w.y, e.y, a1);
      a2 = fmaf(w.z, e.z, a2);
      a3 = fmaf(w.w, e.w, a3);
    }
    float e2v = fmaxf(sbd2[j2] + ((a0+a1)+(a2+a3)), 0.f);
    mv = fmaf(swd3m[j2], e2v, mv);
  }
  tab[idx] = mv;
}

// ---------------- fused agg+gate, 4 rows per block, float4 aggregation ----------------
// grid = NL/4 + NP/4 = 384 blocks x 1024 threads.
__global__ __launch_bounds__(1024) void agg_gate_fused(const float* __restrict__ lc, const float* __restrict__ pc,
                                                       const float* __restrict__ tab,
                                                       const float* __restrict__ lig, const float* __restrict__ poc,
                                                       const float* __restrict__ Wgl, const float* __restrict__ bgl,
                                                       const float* __restrict__ Wgp, const float* __restrict__ bgp,
                                                       float* __restrict__ lenh, float* __restrict__ penh){
  int b = blockIdx.x, t = threadIdx.x;
  bool isLig = (b < NL/4);
  int r0 = isLig ? b*4 : (b - NL/4)*4;
  int n = isLig ? NP : NL;
  const float* myFeat = isLig ? lig : poc;
  const float* otherFeat = isLig ? poc : lig;
  const float* myC = isLig ? lc : pc;
  const float* otC = isLig ? pc : lc;

  __shared__ float w[4*NP];          // 16 KB softmax weights
  __shared__ float sx[4*HDIM];
  __shared__ float sa[4*HDIM];
  __shared__ float part[16*512];     // 32 KB agg partials [jg][row][col]
  __shared__ float gpart[4*2*128];
  __shared__ float redm[16];
  __shared__ float sgm[4], sinv[4];

  int rr = t >> 8, u = t & 255;
  int lane = t & 63, wv = t >> 6;
  int row = r0 + rr;

  if (t < 512) sx[t] = myFeat[(size_t)r0*HDIM + t];

  float cx = myC[row*3+0], cy = myC[row*3+1], cz = myC[row*3+2];
  const float inv_h = (float)(TAB_N - 1) / DMAX;
  int per = n >> 8;                  // 4 (lig) or 2 (poc)

  // ---- Phase A: softmax over partners, per row ----
  float xs[4];
  float lmax = -1e30f;
  for (int k = 0; k < per; k++){
    int j = u + (k << 8);
    float ox = otC[j*3+0], oy = otC[j*3+1], oz = otC[j*3+2];
    float dx = cx-ox, dy = cy-oy, dz = cz-oz;
    float d = sqrtf(fmaf(dx,dx, fmaf(dy,dy, dz*dz)));
    float xf = d * inv_h;
    int i0 = (int)xf;
    i0 = (i0 > TAB_N-2) ? (TAB_N-2) : i0;
    float f = xf - (float)i0;
    float v0 = tab[i0], v1 = tab[i0+1];
    xs[k] = -fmaf(f, v1 - v0, v0);
    lmax = fmaxf(lmax, xs[k]);
  }
  float v = lmax;
  #pragma unroll
  for (int off = 32; off; off >>= 1) v = fmaxf(v, __shfl_down(v, off));
  if (lane == 0) redm[wv] = v;
  __syncthreads();
  if (t < 4) sgm[t] = fmaxf(fmaxf(redm[t*4+0], redm[t*4+1]), fmaxf(redm[t*4+2], redm[t*4+3]));
  __syncthreads();
  float gm = sgm[rr];
  float lsum = 0.f;
  for (int k = 0; k < per; k++){
    float e = __expf(xs[k] - gm);
    w[rr*NP + u + (k << 8)] = e;
    lsum += e;
  }
  v = lsum;
  #pragma unroll
  for (int off = 32; off; off >>= 1) v += __shfl_down(v, off);
  if (lane == 0) redm[wv] = v;
  __syncthreads();
  if (t < 4) sinv[t] = 1.0f / ((redm[t*4+0] + redm[t*4+1]) + (redm[t*4+2] + redm[t*4+3]));
  __syncthreads();

  // ---- Phase B: aggregation, 16 j-groups x 2 row-pairs x 32 float4 cols ----
  {
    int jg = t >> 6;                 // 16 groups
    int rp = (t >> 5) & 1;           // row-pair 0/1
    int c4 = t & 31;                 // float4 column
    int per2 = n >> 4;               // 64 (lig) / 32 (poc)
    int jb0 = jg * per2;
    int rA = rp*2, rB = rp*2 + 1;
    const float4* of4 = (const float4*)otherFeat;
    const float* wA = w + rA*NP;
    const float* wB = w + rB*NP;
    float4 accA = {0,0,0,0}, accB = {0,0,0,0};
    #pragma unroll 4
    for (int jj = 0; jj < per2; jj++){
      int j = jb0 + jj;
      float4 f = of4[(size_t)j*32 + c4];
      float w0 = wA[j], w1 = wB[j];
      accA.x = fmaf(w0, f.x, accA.x); accA.y = fmaf(w0, f.y, accA.y);
      accA.z = fmaf(w0, f.z, accA.z); accA.w = fmaf(w0, f.w, accA.w);
      accB.x = fmaf(w1, f.x, accB.x); accB.y = fmaf(w1, f.y, accB.y);
      accB.z = fmaf(w1, f.z, accB.z); accB.w = fmaf(w1, f.w, accB.w);
    }
    float4* p4 = (float4*)part;      // p4[jg*128 + row*32 + c4]
    p4[jg*128 + rA*32 + c4] = accA;
    p4[jg*128 + rB*32 + c4] = accB;
  }
  __syncthreads();
  {
    float4* p4 = (float4*)part;
    #pragma unroll
    for (int s = 8; s >= 1; s >>= 1){
      if (t < s*128){
        int jg2 = t >> 7, rem = t & 127;
        float4 a = p4[jg2*128 + rem], bb = p4[(jg2+s)*128 + rem];
        a.x += bb.x; a.y += bb.y; a.z += bb.z; a.w += bb.w;
        p4[jg2*128 + rem] = a;
      }
      __syncthreads();
    }
  }
  if (t < 512){
    int r = t >> 7;
    sa[t] = part[t] * sinv[r];
  }
  __syncthreads();

  // ---- Phase C: gate (4 rows x 2 k-halves x 128 cols) ----
  {
    int r = t >> 8;
    int kg = (t >> 7) & 1;
    int col = t & 127;
    const float* Wg = isLig ? Wgl : Wgp;
    const float4* wr = (const float4*)(Wg + (size_t)col*256 + kg*128);
    const float4* inq = (kg == 0) ? (const float4*)(sx + r*128) : (const float4*)(sa + r*128);
    float g = 0.f;
    #pragma unroll 8
    for (int k = 0; k < 32; k++) g += dot4f(wr[k], inq[k]);
    gpart[r*256 + kg*128 + col] = g;
  }
  __syncthreads();
  if (t < 512){
    int r = t >> 7, c = t & 127;
    const float* bg = isLig ? bgl : bgp;
    float g = bg[c] + gpart[r*256 + c] + gpart[r*256 + 128 + c];
    g = 1.0f / (1.0f + __expf(-g));
    float xv = sx[r*128 + c], av = sa[r*128 + c];
    float* dst = isLig ? (lenh + (size_t)(r0+r)*HDIM) : (penh + (size_t)(r0+r)*HDIM);
    dst[c] = fmaf(g, xv - av, av);
  }
}

// ---------------- qkv: [lig_enh; poc_enh] @ Wqkv.T + bqkv (4 rows/block, 384 threads) ----------------
__global__ __launch_bounds__(384) void qkv_kernel(const float* __restrict__ lenh, const float* __restrict__ penh,
                                                  const float* __restrict__ Wqkv, const float* __restrict__ bqkv,
                                                  float* __restrict__ qkvl, float* __restrict__ qkvp){
  int t = threadIdx.x;
  int row0 = blockIdx.x * 4;
  const float* in; float* out; int rloc;
  if (row0 < NL){ in = lenh + (size_t)row0*HDIM; out = qkvl; rloc = row0; }
  else { rloc = row0 - NL; in = penh + (size_t)rloc*HDIM; out = qkvp; }
  __shared__ float sin[4*HDIM];
  for (int idx = t; idx < 4*HDIM; idx += 384) sin[idx] = in[idx];
  __syncthreads();
  float bv = bqkv[t];
  float a0 = bv, a1 = bv, a2 = bv, a3 = bv;
  const float4* wr = (const float4*)(Wqkv + (size_t)t*HDIM);
  const float4* s0 = (const float4*)(sin);
  const float4* s1 = (const float4*)(sin + HDIM);
  const float4* s2 = (const float4*)(sin + 2*HDIM);
  const float4* s3 = (const float4*)(sin + 3*HDIM);
  #pragma unroll 8
  for (int k = 0; k < 32; k++){
    float4 w = wr[k];
    a0 = fmaf(w.x, s0[k].x, fmaf(w.y, s0[k].y, fmaf(w.z, s0[k].z, fmaf(w.w, s0[k].w, a0))));
    a1 = fmaf(w.x, s1[k].x, fmaf(w.y, s1[k].y, fmaf(w.z, s1[k].z, fmaf(w.w, s1[k].w, a1))));
    a2 = fmaf(w.x, s2[k].x, fmaf(w.y, s2[k].y, fmaf(w.z, s2[k].z, fmaf(w.w, s2[k].w, a2))));
    a3 = fmaf(w.x, s3[k].x, fmaf(w.y, s3[k].y, fmaf(w.z, s3[k].z, fmaf(w.w, s3[k].w, a3))));
  }
  out[(size_t)(rloc+0)*384 + t] = a0;
  out[(size_t)(rloc+1)*384 + t] = a1;
  out[(size_t)(rloc+2)*384 + t] = a2;
  out[(size_t)(rloc+3)*384 + t] = a3;
}

// ---------------- flash attention, v3: K/V straight from global (L1/L2), no LDS staging ----------------
__global__ __launch_bounds__(256) void attn_part(const float* __restrict__ qkvl, const float* __restrict__ qkvp,
                                                 float* __restrict__ partL, float* __restrict__ partP){
  int bx = blockIdx.x;
  int t = threadIdx.x;
  const float* qsrc; const float* kvsrc; int qt, slice; bool isLig;
  if (bx < 256){ isLig = true;  qt = bx >> 3; slice = bx & 7; qsrc = qkvl; kvsrc = qkvp; }
  else { int b2 = bx - 256; isLig = false; qt = b2 >> 2; slice = b2 & 3; qsrc = qkvp; kvsrc = qkvl; }
  int g = t >> 7, tt = t & 127;
  int h = tt >> 4, q = tt & 15;
  int j0 = slice*128 + g*64;

  const float4* qp = (const float4*)(qsrc + (size_t)(qt*16+q)*384 + h*16);
  float4 q0 = qp[0], q1 = qp[1], q2 = qp[2], q3 = qp[3];
  float m = -1e30f, l = 0.f;
  float4 O0 = {0,0,0,0}, O1 = {0,0,0,0}, O2 = {0,0,0,0}, O3 = {0,0,0,0};

  for (int tile = 0; tile < 4; tile++){
    int jbase = j0 + tile*16;
    float s[16];
    #pragma unroll
    for (int jj = 0; jj < 16; jj++){
      const float4* kk = (const float4*)(kvsrc + (size_t)(jbase+jj)*384 + 128 + h*16);
      s[jj] = (dot4f(q0, kk[0]) + dot4f(q1, kk[1]) + dot4f(q2, kk[2]) + dot4f(q3, kk[3])) * 0.25f;
    }
    float mt = s[0];
    #pragma unroll
    for (int jj = 1; jj < 16; jj++) mt = fmaxf(mt, s[jj]);
    float mn = fmaxf(m, mt);
    float corr = __expf(m - mn);
    l *= corr;
    O0.x*=corr; O0.y*=corr; O0.z*=corr; O0.w*=corr;
    O1.x*=corr; O1.y*=corr; O1.z*=corr; O1.w*=corr;
    O2.x*=corr; O2.y*=corr; O2.z*=corr; O2.w*=corr;
    O3.x*=corr; O3.y*=corr; O3.z*=corr; O3.w*=corr;
    #pragma unroll
    for (int jj = 0; jj < 16; jj++){
      float p = __expf(s[jj] - mn);
      l += p;
      const float4* vv = (const float4*)(kvsrc + (size_t)(jbase+jj)*384 + 256 + h*16);
      O0.x = fmaf(p, vv[0].x, O0.x); O0.y = fmaf(p, vv[0].y, O0.y);
      O0.z = fmaf(p, vv[0].z, O0.z); O0.w = fmaf(p, vv[0].w, O0.w);
      O1.x = fmaf(p, vv[1].x, O1.x); O1.y = fmaf(p, vv[1].y, O1.y);
      O1.z = fmaf(p, vv[1].z, O1.z); O1.w = fmaf(p, vv[1].w, O1.w);
      O2.x = fmaf(p, vv[2].x, O2.x); O2.y = fmaf(p, vv[2].y, O2.y);
      O2.z = fmaf(p, vv[2].z, O2.z); O2.w = fmaf(p, vv[2].w, O2.w);
      O3.x = fmaf(p, vv[3].x, O3.x); O3.y = fmaf(p, vv[3].y, O3.y);
      O3.z = fmaf(p, vv[3].z, O3.z); O3.w = fmaf(p, vv[3].w, O3.w);
    }
    m = mn;
  }

  // merge the two split-k groups via LDS
  __shared__ float smerge[128*19];   // 9.5 KB
  __syncthreads();
  if (g == 1){
    float* b = smerge + tt*19;
    b[0] = m; b[1] = l;
    b[2]=O0.x; b[3]=O0.y; b[4]=O0.z; b[5]=O0.w;
    b[6]=O1.x; b[7]=O1.y; b[8]=O1.z; b[9]=O1.w;
    b[10]=O2.x; b[11]=O2.y; b[12]=O2.z; b[13]=O2.w;
    b[14]=O3.x; b[15]=O3.y; b[16]=O3.z; b[17]=O3.w;
  }
  __syncthreads();
  if (g == 0){
    const float* b = smerge + tt*19;
    float m1 = b[0], l1 = b[1];
    float M = fmaxf(m, m1);
    float e0 = __expf(m - M), e1 = __expf(m1 - M);
    float L = l*e0 + l1*e1;
    float* dst;
    if (isLig) dst = partL + ((size_t)((qt*16+q)*8 + h)*8 + slice)*18;
    else       dst = partP + ((size_t)((qt*16+q)*8 + h)*4 + slice)*18;
    dst[0] = M; dst[1] = L;
    dst[2]  = O0.x*e0 + b[2]*e1;  dst[3]  = O0.y*e0 + b[3]*e1;
    dst[4]  = O0.z*e0 + b[4]*e1;  dst[5]  = O0.w*e0 + b[5]*e1;
    dst[6]  = O1.x*e0 + b[6]*e1;  dst[7]  = O1.y*e0 + b[7]*e1;
    dst[8]  = O1.z*e0 + b[8]*e1;  dst[9]  = O1.w*e0 + b[9]*e1;
    dst[10] = O2.x*e0 + b[10]*e1; dst[11] = O2.y*e0 + b[11]*e1;
    dst[12] = O2.z*e0 + b[12]*e1; dst[13] = O2.w*e0 + b[13]*e1;
    dst[14] = O3.x*e0 + b[14]*e1; dst[15] = O3.y*e0 + b[15]*e1;
    dst[16] = O3.z*e0 + b[16]*e1; dst[17] = O3.w*e0 + b[17]*e1;
  }
}

// ---------------- merge partials + Wo proj + residual + LayerNorm ----------------
__global__ __launch_bounds__(128) void merge_ln(const float* __restrict__ partL, const float* __restrict__ partP,
                                                const float* __restrict__ lenh, const float* __restrict__ penh,
                                                const float* __restrict__ Wo, const float* __restrict__ bo,
                                                const float* __restrict__ g_l, const float* __restrict__ be_l,
                                                const float* __restrict__ g_p, const float* __restrict__ be_p,
                                                float* __restrict__ out){
  int r = blockIdx.x, t = threadIdx.x;
  int h = t >> 4, c = t & 15;
  int ns; const float* base;
  if (r < NL){ ns = 8; base = partL + ((size_t)(r*8 + h))*8*18; }
  else       { ns = 4; base = partP + ((size_t)((r-NL)*8 + h))*4*18; }
  float M = -1e30f;
  for (int s = 0; s < ns; s++) M = fmaxf(M, base[s*18]);
  float Lsum = 0.f, Osum = 0.f;
  for (int s = 0; s < ns; s++){
    float e = __expf(base[s*18] - M);
    Lsum = fmaf(e, base[s*18+1], Lsum);
    Osum = fmaf(e, base[s*18+2+c], Osum);
  }
  __shared__ float satt[HDIM];
  satt[t] = Osum / Lsum;
  __syncthreads();
  float o = bo[t];
  const float4* wr = (const float4*)(Wo + (size_t)t*HDIM);
  const float4* sv = (const float4*)satt;
  #pragma unroll 8
  for (int k = 0; k < 32; k++) o += dot4f(wr[k], sv[k]);
  const float* enh = (r < NL) ? (lenh + (size_t)r*HDIM) : (penh + (size_t)(r-NL)*HDIM);
  float x = enh[t] + o;
  __shared__ float red[HDIM];
  red[t] = x; __syncthreads();
  #pragma unroll
  for (int s = 64; s > 0; s >>= 1){ if (t < s) red[t] += red[t+s]; __syncthreads(); }
  float mu = red[0] * (1.f/128.f); __syncthreads();
  float dx = x - mu;
  red[t] = dx*dx; __syncthreads();
  #pragma unroll
  for (int s = 64; s > 0; s >>= 1){ if (t < s) red[t] += red[t+s]; __syncthreads(); }
  float var = red[0] * (1.f/128.f);
  float y = dx * rsqrtf(var + 1e-5f);
  if (r < NL){
    y = fmaf(y, g_l[t], be_l[t]);
    out[(size_t)r*HDIM + t] = y;
  } else {
    y = fmaf(y, g_p[t], be_p[t]);
    out[(size_t)NL*HDIM + (size_t)(r-NL)*HDIM + t] = y;
  }
}

extern "C" void kernel_launch(void* const* d_in, const int* in_sizes, int n_in,
                              void* d_out, int out_size, void* d_ws, size_t ws_size,
                              hipStream_t stream){
  const float* lf   = (const float*)d_in[0];
  const float* pf   = (const float*)d_in[1];
  const float* lc   = (const float*)d_in[2];
  const float* pc   = (const float*)d_in[3];
  const float* Wl   = (const float*)d_in[4];
  const float* bl   = (const float*)d_in[5];
  const float* Wp   = (const float*)d_in[6];
  const float* bp   = (const float*)d_in[7];
  const float* Wd1  = (const float*)d_in[8];
  const float* bd1  = (const float*)d_in[9];
  const float* Wd2  = (const float*)d_in[10];
  const float* bd2  = (const float*)d_in[11];
  const float* Wd3  = (const float*)d_in[12];
  const float* bd3  = (const float*)d_in[13];
  const float* Wgl  = (const float*)d_in[14];
  const float* bgl  = (const float*)d_in[15];
  const float* Wgp  = (const float*)d_in[16];
  const float* bgp  = (const float*)d_in[17];
  const float* Wqkv = (const float*)d_in[18];
  const float* bqkv = (const float*)d_in[19];
  const float* Wo   = (const float*)d_in[20];
  const float* bo   = (const float*)d_in[21];
  const float* g_l  = (const float*)d_in[22];
  const float* be_l = (const float*)d_in[23];
  const float* g_p  = (const float*)d_in[24];
  const float* be_p = (const float*)d_in[25];

  float* ws  = (float*)d_ws;
  float* out = (float*)d_out;
  float* lig   = ws + LIG_OFF;
  float* poc   = ws + POC_OFF;
  float* lenh  = ws + LENH_OFF;
  float* penh  = ws + PENH_OFF;
  float* qkvl  = ws + QKVL_OFF;
  float* qkvp  = ws + QKVP_OFF;
  float* partL = ws + PARTL_OFF;
  float* partP = ws + PARTP_OFF;
  float* tab   = ws + TAB_OFF;   // aliases qkvl region; consumed before qkv_kernel writes

  table_kernel<<<TAB_N/256, 256, 0, stream>>>(Wd1, bd1, Wd2, bd2, Wd3, bd3, tab);
  proj_kernel<<<384, 128, 0, stream>>>(lf, pf, Wl, bl, Wp, bp, lig, poc);
  agg_gate_fused<<<NL/4 + NP/4, 1024, 0, stream>>>(lc, pc, tab, lig, poc, Wgl, bgl, Wgp, bgp, lenh, penh);
  qkv_kernel<<<384, 384, 0, stream>>>(lenh, penh, Wqkv, bqkv, qkvl, qkvp);
  attn_part<<<512, 256, 0, stream>>>(qkvl, qkvp, partL, partP);
  merge_ln<<<1536, 128, 0, stream>>>(partL, partP, lenh, penh, Wo, bo, g_l, be_l, g_p, be_p, out);
}

// Round 8
// 237.506 us; speedup vs baseline: 1.0331x; 1.0331x over previous
//
#include <hip/hip_runtime.h>
#include <math.h>

#define NL 512
#define NP 1024
#define HDIM 128

#define TAB_N 8192
#define DMAX 34.65f

// ---- workspace layout (float offsets) ----
#define M_OFF    128
#define LIG_OFF  (M_OFF + NL*NP)              // lig proj 512x128
#define POC_OFF  (LIG_OFF + NL*HDIM)          // poc proj 1024x128
#define LENH_OFF (POC_OFF + NP*HDIM)          // lig_enh 512x128
#define PENH_OFF (LENH_OFF + NL*HDIM)         // poc_enh 1024x128
#define QKVL_OFF (PENH_OFF + NP*HDIM)         // qkv for lig_enh 512x384 (aliased by m(d) table earlier)
#define QKVP_OFF (QKVL_OFF + NL*384)          // qkv for poc_enh 1024x384
#define PARTL_OFF (QKVP_OFF + NP*384)         // lig partials: [512][8 h][8 slices][18]
#define PARTP_OFF (PARTL_OFF + 512*8*8*18)    // poc partials: [1024][8 h][4 slices][18]
#define TAB_OFF  QKVL_OFF                     // table consumed by agg_gate before qkv_kernel writes here

__device__ __forceinline__ float dot4f(float4 a, float4 b){
  return fmaf(a.x,b.x, fmaf(a.y,b.y, fmaf(a.z,b.z, a.w*b.w)));
}

// ---------------- proj: lig = LF@Wl.T+bl ; poc = PF@Wp.T+bp (4 rows/block) ----------------
__global__ __launch_bounds__(128) void proj_kernel(const float* __restrict__ lf, const float* __restrict__ pf,
                                                   const float* __restrict__ Wl, const float* __restrict__ bl,
                                                   const float* __restrict__ Wp, const float* __restrict__ bp,
                                                   float* __restrict__ lig, float* __restrict__ poc){
  int t = threadIdx.x;
  int row0 = blockIdx.x * 4;
  const float* in; const float* W; const float* bias; float* out;
  if (row0 < NL){ in = lf + (size_t)row0*HDIM; W = Wl; bias = bl; out = lig + (size_t)row0*HDIM; }
  else { int r = row0 - NL; in = pf + (size_t)r*HDIM; W = Wp; bias = bp; out = poc + (size_t)r*HDIM; }
  __shared__ float sin[4*HDIM];
  for (int idx = t; idx < 4*HDIM; idx += 128) sin[idx] = in[idx];
  __syncthreads();
  float bv = bias[t];
  float a0 = bv, a1 = bv, a2 = bv, a3 = bv;
  const float4* wr = (const float4*)(W + (size_t)t*HDIM);
  const float4* s0 = (const float4*)(sin);
  const float4* s1 = (const float4*)(sin + HDIM);
  const float4* s2 = (const float4*)(sin + 2*HDIM);
  const float4* s3 = (const float4*)(sin + 3*HDIM);
  #pragma unroll 8
  for (int k = 0; k < 32; k++){
    float4 w = wr[k];
    a0 = fmaf(w.x, s0[k].x, fmaf(w.y, s0[k].y, fmaf(w.z, s0[k].z, fmaf(w.w, s0[k].w, a0))));
    a1 = fmaf(w.x, s1[k].x, fmaf(w.y, s1[k].y, fmaf(w.z, s1[k].z, fmaf(w.w, s1[k].w, a1))));
    a2 = fmaf(w.x, s2[k].x, fmaf(w.y, s2[k].y, fmaf(w.z, s2[k].z, fmaf(w.w, s2[k].w, a2))));
    a3 = fmaf(w.x, s3[k].x, fmaf(w.y, s3[k].y, fmaf(w.z, s3[k].z, fmaf(w.w, s3[k].w, a3))));
  }
  out[t] = a0; out[HDIM + t] = a1; out[2*HDIM + t] = a2; out[3*HDIM + t] = a3;
}

// ---------------- table: tab[idx] = m(d_idx) via full MLP; wd3m computed inline ----------------
__global__ __launch_bounds__(256) void table_kernel(const float* __restrict__ Wd1, const float* __restrict__ bd1,
                                                    const float* __restrict__ Wd2, const float* __restrict__ bd2,
                                                    const float* __restrict__ Wd3, const float* __restrict__ bd3,
                                                    float* __restrict__ tab){
  __shared__ float sWd1[32], sbd1[32], sWd2[2048], sbd2[64], swd3m[64];
  __shared__ float sbd3m;
  int t = threadIdx.x;
  int idx = blockIdx.x * 256 + t;
  if (t < 64){
    float s = 0.f;
    #pragma unroll 8
    for (int i = 0; i < 128; i++) s += Wd3[i*64 + t];
    swd3m[t] = s * (1.f/128.f);
  } else if (t == 64){
    float s = 0.f;
    for (int i = 0; i < 128; i++) s += bd3[i];
    sbd3m = s * (1.f/128.f);
  } else if (t >= 128 && t < 160){ sWd1[t-128] = Wd1[t-128]; sbd1[t-128] = bd1[t-128]; }
  else if (t >= 160 && t < 224){ sbd2[t-160] = bd2[t-160]; }
  for (int k = t; k < 2048; k += 256) sWd2[k] = Wd2[k];
  __syncthreads();

  float d = (float)idx * (DMAX / (float)(TAB_N - 1));

  float4 e1q[8];
  const float4* w1q = (const float4*)sWd1;
  const float4* b1q = (const float4*)sbd1;
  #pragma unroll
  for (int k4 = 0; k4 < 8; k4++){
    float4 w = w1q[k4], b = b1q[k4];
    float4 e;
    e.x = fmaxf(fmaf(d, w.x, b.x), 0.f);
    e.y = fmaxf(fmaf(d, w.y, b.y), 0.f);
    e.z = fmaxf(fmaf(d, w.z, b.z), 0.f);
    e.w = fmaxf(fmaf(d, w.w, b.w), 0.f);
    e1q[k4] = e;
  }
  float mv = sbd3m;
  #pragma unroll 4
  for (int j2 = 0; j2 < 64; j2++){
    const float4* wrow = (const float4*)(sWd2 + j2*32);
    float a0 = 0.f, a1 = 0.f, a2 = 0.f, a3 = 0.f;
    #pragma unroll
    for (int k4 = 0; k4 < 8; k4++){
      float4 w = wrow[k4], e = e1q[k4];
      a0 = fmaf(w.x, e.x, a0);
      a1 = fmaf(w.y, e.y, a1);
      a2 = fmaf(w.z, e.z, a2);
      a3 = fmaf(w.w, e.w, a3);
    }
    float e2v = fmaxf(sbd2[j2] + ((a0+a1)+(a2+a3)), 0.f);
    mv = fmaf(swd3m[j2], e2v, mv);
  }
  tab[idx] = mv;
}

// ---------------- fused agg+gate, 8 rows per block ----------------
// grid = NL/8 + NP/8 = 192 blocks x 1024 threads.
// Traffic: each block reads partner features once -> 64 MB total (vs 128 MB at R=4).
__global__ __launch_bounds__(1024) void agg_gate_fused(const float* __restrict__ lc, const float* __restrict__ pc,
                                                       const float* __restrict__ tab,
                                                       const float* __restrict__ lig, const float* __restrict__ poc,
                                                       const float* __restrict__ Wgl, const float* __restrict__ bgl,
                                                       const float* __restrict__ Wgp, const float* __restrict__ bgp,
                                                       float* __restrict__ lenh, float* __restrict__ penh){
  int b = blockIdx.x, t = threadIdx.x;
  bool isLig = (b < NL/8);
  int r0 = isLig ? b*8 : (b - NL/8)*8;
  int n = isLig ? NP : NL;
  const float* myFeat = isLig ? lig : poc;
  const float* otherFeat = isLig ? poc : lig;
  const float* myC = isLig ? lc : pc;
  const float* otC = isLig ? pc : lc;

  __shared__ float w[8*NP];          // 32 KB softmax weights
  __shared__ float sx[8*HDIM];       // 4 KB own features
  __shared__ float sa[8*HDIM];       // 4 KB aggregated
  __shared__ float part[8192];       // 32 KB agg partials [jg(8)][row(8)][col(128)]
  __shared__ float redm[16];
  __shared__ float sgm[8], sinv[8];

  int rr = t >> 7, u = t & 127;      // row-in-block, partner-lane
  int lane = t & 63, wv = t >> 6;
  int row = r0 + rr;

  for (int k = t; k < 8*HDIM; k += 1024) sx[k] = myFeat[(size_t)r0*HDIM + k];

  float cx = myC[row*3+0], cy = myC[row*3+1], cz = myC[row*3+2];
  const float inv_h = (float)(TAB_N - 1) / DMAX;
  int per = n >> 7;                  // 8 (lig) or 4 (poc)

  // ---- Phase A: softmax over partners, per row ----
  float xs[8];
  float lmax = -1e30f;
  for (int k = 0; k < per; k++){
    int j = u + (k << 7);
    float ox = otC[j*3+0], oy = otC[j*3+1], oz = otC[j*3+2];
    float dx = cx-ox, dy = cy-oy, dz = cz-oz;
    float d = sqrtf(fmaf(dx,dx, fmaf(dy,dy, dz*dz)));
    float xf = d * inv_h;
    int i0 = (int)xf;
    i0 = (i0 > TAB_N-2) ? (TAB_N-2) : i0;
    float f = xf - (float)i0;
    float v0 = tab[i0], v1 = tab[i0+1];
    xs[k] = -fmaf(f, v1 - v0, v0);
    lmax = fmaxf(lmax, xs[k]);
  }
  float v = lmax;
  #pragma unroll
  for (int off = 32; off; off >>= 1) v = fmaxf(v, __shfl_down(v, off));
  if (lane == 0) redm[wv] = v;
  __syncthreads();
  if (t < 8) sgm[t] = fmaxf(redm[t*2], redm[t*2+1]);   // 2 waves per row
  __syncthreads();
  float gm = sgm[rr];
  float lsum = 0.f;
  for (int k = 0; k < per; k++){
    float e = __expf(xs[k] - gm);
    w[rr*NP + u + (k << 7)] = e;
    lsum += e;
  }
  v = lsum;
  #pragma unroll
  for (int off = 32; off; off >>= 1) v += __shfl_down(v, off);
  if (lane == 0) redm[wv] = v;
  __syncthreads();
  if (t < 8) sinv[t] = 1.0f / (redm[t*2] + redm[t*2+1]);
  __syncthreads();

  // ---- Phase B: aggregation, 8 j-groups x 4 row-pairs x 32 float4 cols ----
  {
    int jg = t >> 7;                 // 8 groups (wave-uniform)
    int rp = (t >> 5) & 3;           // row-pair
    int c4 = t & 31;                 // float4 column
    int per2 = n >> 3;               // 128 (lig) / 64 (poc)
    int jb0 = jg * per2;
    int rA = rp*2, rB = rp*2 + 1;
    const float4* of4 = (const float4*)otherFeat;
    const float* wA = w + rA*NP;
    const float* wB = w + rB*NP;
    float4 accA = {0,0,0,0}, accB = {0,0,0,0};
    #pragma unroll 4
    for (int jj = 0; jj < per2; jj++){
      int j = jb0 + jj;
      float4 f = of4[(size_t)j*32 + c4];
      float w0 = wA[j], w1 = wB[j];
      accA.x = fmaf(w0, f.x, accA.x); accA.y = fmaf(w0, f.y, accA.y);
      accA.z = fmaf(w0, f.z, accA.z); accA.w = fmaf(w0, f.w, accA.w);
      accB.x = fmaf(w1, f.x, accB.x); accB.y = fmaf(w1, f.y, accB.y);
      accB.z = fmaf(w1, f.z, accB.z); accB.w = fmaf(w1, f.w, accB.w);
    }
    float4* p4 = (float4*)part;      // p4[jg*256 + row*32 + c4]
    p4[jg*256 + rA*32 + c4] = accA;
    p4[jg*256 + rB*32 + c4] = accB;
  }
  __syncthreads();
  {
    float4* p4 = (float4*)part;
    #pragma unroll
    for (int s = 4; s >= 1; s >>= 1){
      if (t < s*256) p4[t].x += 0.f;   // keep compiler from reordering (no-op)
      if (t < s*256){
        float4 a = p4[t], bb = p4[t + s*256];
        a.x += bb.x; a.y += bb.y; a.z += bb.z; a.w += bb.w;
        p4[t] = a;
      }
      __syncthreads();
    }
  }
  if (t < 1024){
    int r = t >> 7;
    sa[t] = part[t] * sinv[r];
  }
  __syncthreads();

  // ---- Phase C: gate — each thread computes the full 256-wide dot for (row, col) ----
  {
    int r = t >> 7, col = t & 127;
    const float* Wg = isLig ? Wgl : Wgp;
    const float* bg = isLig ? bgl : bgp;
    const float4* wr = (const float4*)(Wg + (size_t)col*256);
    const float4* xq = (const float4*)(sx + r*128);
    const float4* aq = (const float4*)(sa + r*128);
    float g = bg[col];
    #pragma unroll 8
    for (int k = 0; k < 32; k++) g += dot4f(wr[k], xq[k]);
    #pragma unroll 8
    for (int k = 0; k < 32; k++) g += dot4f(wr[32+k], aq[k]);
    g = 1.0f / (1.0f + __expf(-g));
    float xv = sx[r*128 + col], av = sa[r*128 + col];
    float* dst = isLig ? (lenh + (size_t)(r0+r)*HDIM) : (penh + (size_t)(r0+r)*HDIM);
    dst[col] = fmaf(g, xv - av, av);   // g*x + (1-g)*a
  }
}

// ---------------- qkv: [lig_enh; poc_enh] @ Wqkv.T + bqkv (4 rows/block, 384 threads) ----------------
__global__ __launch_bounds__(384) void qkv_kernel(const float* __restrict__ lenh, const float* __restrict__ penh,
                                                  const float* __restrict__ Wqkv, const float* __restrict__ bqkv,
                                                  float* __restrict__ qkvl, float* __restrict__ qkvp){
  int t = threadIdx.x;
  int row0 = blockIdx.x * 4;
  const float* in; float* out; int rloc;
  if (row0 < NL){ in = lenh + (size_t)row0*HDIM; out = qkvl; rloc = row0; }
  else { rloc = row0 - NL; in = penh + (size_t)rloc*HDIM; out = qkvp; }
  __shared__ float sin[4*HDIM];
  for (int idx = t; idx < 4*HDIM; idx += 384) sin[idx] = in[idx];
  __syncthreads();
  float bv = bqkv[t];
  float a0 = bv, a1 = bv, a2 = bv, a3 = bv;
  const float4* wr = (const float4*)(Wqkv + (size_t)t*HDIM);
  const float4* s0 = (const float4*)(sin);
  const float4* s1 = (const float4*)(sin + HDIM);
  const float4* s2 = (const float4*)(sin + 2*HDIM);
  const float4* s3 = (const float4*)(sin + 3*HDIM);
  #pragma unroll 8
  for (int k = 0; k < 32; k++){
    float4 w = wr[k];
    a0 = fmaf(w.x, s0[k].x, fmaf(w.y, s0[k].y, fmaf(w.z, s0[k].z, fmaf(w.w, s0[k].w, a0))));
    a1 = fmaf(w.x, s1[k].x, fmaf(w.y, s1[k].y, fmaf(w.z, s1[k].z, fmaf(w.w, s1[k].w, a1))));
    a2 = fmaf(w.x, s2[k].x, fmaf(w.y, s2[k].y, fmaf(w.z, s2[k].z, fmaf(w.w, s2[k].w, a2))));
    a3 = fmaf(w.x, s3[k].x, fmaf(w.y, s3[k].y, fmaf(w.z, s3[k].z, fmaf(w.w, s3[k].w, a3))));
  }
  out[(size_t)(rloc+0)*384 + t] = a0;
  out[(size_t)(rloc+1)*384 + t] = a1;
  out[(size_t)(rloc+2)*384 + t] = a2;
  out[(size_t)(rloc+3)*384 + t] = a3;
}

// ---------------- flash attention, v2 (LDS staging, h-major lanes; 2 split-k groups per block) ----------------
__global__ __launch_bounds__(256) void attn_part(const float* __restrict__ qkvl, const float* __restrict__ qkvp,
                                                 float* __restrict__ partL, float* __restrict__ partP){
  int bx = blockIdx.x;
  int t = threadIdx.x;
  const float* qsrc; const float* kvsrc; int qt, slice; bool isLig;
  if (bx < 256){ isLig = true;  qt = bx >> 3; slice = bx & 7; qsrc = qkvl; kvsrc = qkvp; }
  else { int b2 = bx - 256; isLig = false; qt = b2 >> 2; slice = b2 & 3; qsrc = qkvp; kvsrc = qkvl; }
  int g = t >> 7, tt = t & 127;
  int h = tt >> 4, q = tt & 15;
  int j0 = slice*128 + g*64;

  const float4* qp = (const float4*)(qsrc + (size_t)(qt*16+q)*384 + h*16);
  float4 q0 = qp[0], q1 = qp[1], q2 = qp[2], q3 = qp[3];
  float m = -1e30f, l = 0.f;
  float4 O0 = {0,0,0,0}, O1 = {0,0,0,0}, O2 = {0,0,0,0}, O3 = {0,0,0,0};

  __shared__ float sKV[8192];
  float* myKV = sKV + g*4096;

  for (int tile = 0; tile < 4; tile++){
    int jbase = j0 + tile*16;
    __syncthreads();
    #pragma unroll
    for (int n = 0; n < 8; n++){
      int v4 = tt + n*128;
      int jj = v4 >> 6, c4 = v4 & 63;
      ((float4*)myKV)[(size_t)jj*64 + c4] = *(const float4*)(kvsrc + (size_t)(jbase+jj)*384 + 128 + c4*4);
    }
    __syncthreads();
    float s[16];
    #pragma unroll
    for (int jj = 0; jj < 16; jj++){
      const float4* kk = (const float4*)(myKV + jj*256 + h*16);
      s[jj] = (dot4f(q0, kk[0]) + dot4f(q1, kk[1]) + dot4f(q2, kk[2]) + dot4f(q3, kk[3])) * 0.25f;
    }
    float mt = s[0];
    #pragma unroll
    for (int jj = 1; jj < 16; jj++) mt = fmaxf(mt, s[jj]);
    float mn = fmaxf(m, mt);
    float corr = __expf(m - mn);
    l *= corr;
    O0.x*=corr; O0.y*=corr; O0.z*=corr; O0.w*=corr;
    O1.x*=corr; O1.y*=corr; O1.z*=corr; O1.w*=corr;
    O2.x*=corr; O2.y*=corr; O2.z*=corr; O2.w*=corr;
    O3.x*=corr; O3.y*=corr; O3.z*=corr; O3.w*=corr;
    #pragma unroll
    for (int jj = 0; jj < 16; jj++){
      float p = __expf(s[jj] - mn);
      l += p;
      const float4* vv = (const float4*)(myKV + jj*256 + 128 + h*16);
      O0.x = fmaf(p, vv[0].x, O0.x); O0.y = fmaf(p, vv[0].y, O0.y);
      O0.z = fmaf(p, vv[0].z, O0.z); O0.w = fmaf(p, vv[0].w, O0.w);
      O1.x = fmaf(p, vv[1].x, O1.x); O1.y = fmaf(p, vv[1].y, O1.y);
      O1.z = fmaf(p, vv[1].z, O1.z); O1.w = fmaf(p, vv[1].w, O1.w);
      O2.x = fmaf(p, vv[2].x, O2.x); O2.y = fmaf(p, vv[2].y, O2.y);
      O2.z = fmaf(p, vv[2].z, O2.z); O2.w = fmaf(p, vv[2].w, O2.w);
      O3.x = fmaf(p, vv[3].x, O3.x); O3.y = fmaf(p, vv[3].y, O3.y);
      O3.z = fmaf(p, vv[3].z, O3.z); O3.w = fmaf(p, vv[3].w, O3.w);
    }
    m = mn;
  }

  __syncthreads();
  float* smerge = sKV;
  if (g == 1){
    float* b = smerge + tt*19;
    b[0] = m; b[1] = l;
    b[2]=O0.x; b[3]=O0.y; b[4]=O0.z; b[5]=O0.w;
    b[6]=O1.x; b[7]=O1.y; b[8]=O1.z; b[9]=O1.w;
    b[10]=O2.x; b[11]=O2.y; b[12]=O2.z; b[13]=O2.w;
    b[14]=O3.x; b[15]=O3.y; b[16]=O3.z; b[17]=O3.w;
  }
  __syncthreads();
  if (g == 0){
    const float* b = smerge + tt*19;
    float m1 = b[0], l1 = b[1];
    float M = fmaxf(m, m1);
    float e0 = __expf(m - M), e1 = __expf(m1 - M);
    float L = l*e0 + l1*e1;
    float* dst;
    if (isLig) dst = partL + ((size_t)((qt*16+q)*8 + h)*8 + slice)*18;
    else       dst = partP + ((size_t)((qt*16+q)*8 + h)*4 + slice)*18;
    dst[0] = M; dst[1] = L;
    dst[2]  = O0.x*e0 + b[2]*e1;  dst[3]  = O0.y*e0 + b[3]*e1;
    dst[4]  = O0.z*e0 + b[4]*e1;  dst[5]  = O0.w*e0 + b[5]*e1;
    dst[6]  = O1.x*e0 + b[6]*e1;  dst[7]  = O1.y*e0 + b[7]*e1;
    dst[8]  = O1.z*e0 + b[8]*e1;  dst[9]  = O1.w*e0 + b[9]*e1;
    dst[10] = O2.x*e0 + b[10]*e1; dst[11] = O2.y*e0 + b[11]*e1;
    dst[12] = O2.z*e0 + b[12]*e1; dst[13] = O2.w*e0 + b[13]*e1;
    dst[14] = O3.x*e0 + b[14]*e1; dst[15] = O3.y*e0 + b[15]*e1;
    dst[16] = O3.z*e0 + b[16]*e1; dst[17] = O3.w*e0 + b[17]*e1;
  }
}

// ---------------- merge partials + Wo proj + residual + LayerNorm ----------------
__global__ __launch_bounds__(128) void merge_ln(const float* __restrict__ partL, const float* __restrict__ partP,
                                                const float* __restrict__ lenh, const float* __restrict__ penh,
                                                const float* __restrict__ Wo, const float* __restrict__ bo,
                                                const float* __restrict__ g_l, const float* __restrict__ be_l,
                                                const float* __restrict__ g_p, const float* __restrict__ be_p,
                                                float* __restrict__ out){
  int r = blockIdx.x, t = threadIdx.x;
  int h = t >> 4, c = t & 15;
  int ns; const float* base;
  if (r < NL){ ns = 8; base = partL + ((size_t)(r*8 + h))*8*18; }
  else       { ns = 4; base = partP + ((size_t)((r-NL)*8 + h))*4*18; }
  float M = -1e30f;
  for (int s = 0; s < ns; s++) M = fmaxf(M, base[s*18]);
  float Lsum = 0.f, Osum = 0.f;
  for (int s = 0; s < ns; s++){
    float e = __expf(base[s*18] - M);
    Lsum = fmaf(e, base[s*18+1], Lsum);
    Osum = fmaf(e, base[s*18+2+c], Osum);
  }
  __shared__ float satt[HDIM];
  satt[t] = Osum / Lsum;
  __syncthreads();
  float o = bo[t];
  const float4* wr = (const float4*)(Wo + (size_t)t*HDIM);
  const float4* sv = (const float4*)satt;
  #pragma unroll 8
  for (int k = 0; k < 32; k++) o += dot4f(wr[k], sv[k]);
  const float* enh = (r < NL) ? (lenh + (size_t)r*HDIM) : (penh + (size_t)(r-NL)*HDIM);
  float x = enh[t] + o;
  __shared__ float red[HDIM];
  red[t] = x; __syncthreads();
  #pragma unroll
  for (int s = 64; s > 0; s >>= 1){ if (t < s) red[t] += red[t+s]; __syncthreads(); }
  float mu = red[0] * (1.f/128.f); __syncthreads();
  float dx = x - mu;
  red[t] = dx*dx; __syncthreads();
  #pragma unroll
  for (int s = 64; s > 0; s >>= 1){ if (t < s) red[t] += red[t+s]; __syncthreads(); }
  float var = red[0] * (1.f/128.f);
  float y = dx * rsqrtf(var + 1e-5f);
  if (r < NL){
    y = fmaf(y, g_l[t], be_l[t]);
    out[(size_t)r*HDIM + t] = y;
  } else {
    y = fmaf(y, g_p[t], be_p[t]);
    out[(size_t)NL*HDIM + (size_t)(r-NL)*HDIM + t] = y;
  }
}

extern "C" void kernel_launch(void* const* d_in, const int* in_sizes, int n_in,
                              void* d_out, int out_size, void* d_ws, size_t ws_size,
                              hipStream_t stream){
  const float* lf   = (const float*)d_in[0];
  const float* pf   = (const float*)d_in[1];
  const float* lc   = (const float*)d_in[2];
  const float* pc   = (const float*)d_in[3];
  const float* Wl   = (const float*)d_in[4];
  const float* bl   = (const float*)d_in[5];
  const float* Wp   = (const float*)d_in[6];
  const float* bp   = (const float*)d_in[7];
  const float* Wd1  = (const float*)d_in[8];
  const float* bd1  = (const float*)d_in[9];
  const float* Wd2  = (const float*)d_in[10];
  const float* bd2  = (const float*)d_in[11];
  const float* Wd3  = (const float*)d_in[12];
  const float* bd3  = (const float*)d_in[13];
  const float* Wgl  = (const float*)d_in[14];
  const float* bgl  = (const float*)d_in[15];
  const float* Wgp  = (const float*)d_in[16];
  const float* bgp  = (const float*)d_in[17];
  const float* Wqkv = (const float*)d_in[18];
  const float* bqkv = (const float*)d_in[19];
  const float* Wo   = (const float*)d_in[20];
  const float* bo   = (const float*)d_in[21];
  const float* g_l  = (const float*)d_in[22];
  const float* be_l = (const float*)d_in[23];
  const float* g_p  = (const float*)d_in[24];
  const float* be_p = (const float*)d_in[25];

  float* ws  = (float*)d_ws;
  float* out = (float*)d_out;
  float* lig   = ws + LIG_OFF;
  float* poc   = ws + POC_OFF;
  float* lenh  = ws + LENH_OFF;
  float* penh  = ws + PENH_OFF;
  float* qkvl  = ws + QKVL_OFF;
  float* qkvp  = ws + QKVP_OFF;
  float* partL = ws + PARTL_OFF;
  float* partP = ws + PARTP_OFF;
  float* tab   = ws + TAB_OFF;   // aliases qkvl region; consumed before qkv_kernel writes

  table_kernel<<<TAB_N/256, 256, 0, stream>>>(Wd1, bd1, Wd2, bd2, Wd3, bd3, tab);
  proj_kernel<<<384, 128, 0, stream>>>(lf, pf, Wl, bl, Wp, bp, lig, poc);
  agg_gate_fused<<<NL/8 + NP/8, 1024, 0, stream>>>(lc, pc, tab, lig, poc, Wgl, bgl, Wgp, bgp, lenh, penh);
  qkv_kernel<<<384, 384, 0, stream>>>(lenh, penh, Wqkv, bqkv, qkvl, qkvp);
  attn_part<<<512, 256, 0, stream>>>(qkvl, qkvp, partL, partP);
  merge_ln<<<1536, 128, 0, stream>>>(partL, partP, lenh, penh, Wo, bo, g_l, be_l, g_p, be_p, out);
}

// Round 9
// 209.356 us; speedup vs baseline: 1.1720x; 1.1345x over previous
//
#include <hip/hip_runtime.h>
#include <math.h>

#define NL 512
#define NP 1024
#define HDIM 128

#define TAB_N 8192
#define DMAX 34.65f

// ---- workspace layout (float offsets) ----
#define M_OFF    128
// transposed weights live in the (otherwise free) m-region:
#define WLT_OFF  (M_OFF)                      // WlT  [128][128]
#define WPT_OFF  (M_OFF + 16384)              // WpT  [128][128]
#define WQT_OFF  (M_OFF + 32768)              // WqkvT[128][384]
#define WOT_OFF  (M_OFF + 81920)              // WoT  [128][128]
#define WGLT_OFF (M_OFF + 98304)              // WglT [256][128]
#define WGPT_OFF (M_OFF + 131072)             // WgpT [256][128]
#define LIG_OFF  (M_OFF + NL*NP)              // lig proj 512x128
#define POC_OFF  (LIG_OFF + NL*HDIM)          // poc proj 1024x128
#define LENH_OFF (POC_OFF + NP*HDIM)          // lig_enh 512x128
#define PENH_OFF (LENH_OFF + NL*HDIM)         // poc_enh 1024x128
#define QKVL_OFF (PENH_OFF + NP*HDIM)         // qkv for lig_enh 512x384 (aliased by m(d) table earlier)
#define QKVP_OFF (QKVL_OFF + NL*384)          // qkv for poc_enh 1024x384
#define PARTL_OFF (QKVP_OFF + NP*384)         // lig partials: [512][8 h][8 slices][18]
#define PARTP_OFF (PARTL_OFF + 512*8*8*18)    // poc partials: [1024][8 h][4 slices][18]
#define TAB_OFF  QKVL_OFF                     // table consumed by agg_gate before qkv_kernel writes here

__device__ __forceinline__ float dot4f(float4 a, float4 b){
  return fmaf(a.x,b.x, fmaf(a.y,b.y, fmaf(a.z,b.z, a.w*b.w)));
}

// ---------------- transpose all matvec weights: src[O][K] -> dst[K][O] ----------------
__device__ __forceinline__ void tpose(const float* __restrict__ src, float* __restrict__ dst,
                                      int O, int K, int blk0, int t){
  int e0 = blk0*1024 + t*4;
  #pragma unroll
  for (int i = 0; i < 4; i++){
    int e = e0 + i;
    int o = e / K, k = e - o*K;
    dst[(size_t)k*O + o] = src[(size_t)o*K + k];
  }
}
__global__ __launch_bounds__(256) void transpose_all(const float* __restrict__ Wl, const float* __restrict__ Wp,
                                                     const float* __restrict__ Wqkv, const float* __restrict__ Wo,
                                                     const float* __restrict__ Wgl, const float* __restrict__ Wgp,
                                                     float* __restrict__ ws){
  int b = blockIdx.x, t = threadIdx.x;
  if      (b < 16)  tpose(Wl,   ws + WLT_OFF,  128, 128, b,       t);
  else if (b < 32)  tpose(Wp,   ws + WPT_OFF,  128, 128, b - 16,  t);
  else if (b < 80)  tpose(Wqkv, ws + WQT_OFF,  384, 128, b - 32,  t);
  else if (b < 96)  tpose(Wo,   ws + WOT_OFF,  128, 128, b - 80,  t);
  else if (b < 128) tpose(Wgl,  ws + WGLT_OFF, 128, 256, b - 96,  t);
  else              tpose(Wgp,  ws + WGPT_OFF, 128, 256, b - 128, t);
}

// ---------------- table: tab[idx] = m(d_idx) via full MLP; wd3m computed inline ----------------
__global__ __launch_bounds__(256) void table_kernel(const float* __restrict__ Wd1, const float* __restrict__ bd1,
                                                    const float* __restrict__ Wd2, const float* __restrict__ bd2,
                                                    const float* __restrict__ Wd3, const float* __restrict__ bd3,
                                                    float* __restrict__ tab){
  __shared__ float sWd1[32], sbd1[32], sWd2[2048], sbd2[64], swd3m[64];
  __shared__ float sbd3m;
  int t = threadIdx.x;
  int idx = blockIdx.x * 256 + t;
  if (t < 64){
    float s = 0.f;
    #pragma unroll 8
    for (int i = 0; i < 128; i++) s += Wd3[i*64 + t];
    swd3m[t] = s * (1.f/128.f);
  } else if (t == 64){
    float s = 0.f;
    for (int i = 0; i < 128; i++) s += bd3[i];
    sbd3m = s * (1.f/128.f);
  } else if (t >= 128 && t < 160){ sWd1[t-128] = Wd1[t-128]; sbd1[t-128] = bd1[t-128]; }
  else if (t >= 160 && t < 224){ sbd2[t-160] = bd2[t-160]; }
  for (int k = t; k < 2048; k += 256) sWd2[k] = Wd2[k];
  __syncthreads();

  float d = (float)idx * (DMAX / (float)(TAB_N - 1));

  float4 e1q[8];
  const float4* w1q = (const float4*)sWd1;
  const float4* b1q = (const float4*)sbd1;
  #pragma unroll
  for (int k4 = 0; k4 < 8; k4++){
    float4 w = w1q[k4], b = b1q[k4];
    float4 e;
    e.x = fmaxf(fmaf(d, w.x, b.x), 0.f);
    e.y = fmaxf(fmaf(d, w.y, b.y), 0.f);
    e.z = fmaxf(fmaf(d, w.z, b.z), 0.f);
    e.w = fmaxf(fmaf(d, w.w, b.w), 0.f);
    e1q[k4] = e;
  }
  float mv = sbd3m;
  #pragma unroll 4
  for (int j2 = 0; j2 < 64; j2++){
    const float4* wrow = (const float4*)(sWd2 + j2*32);
    float a0 = 0.f, a1 = 0.f, a2 = 0.f, a3 = 0.f;
    #pragma unroll
    for (int k4 = 0; k4 < 8; k4++){
      float4 w = wrow[k4], e = e1q[k4];
      a0 = fmaf(w.x, e.x, a0);
      a1 = fmaf(w.y, e.y, a1);
      a2 = fmaf(w.z, e.z, a2);
      a3 = fmaf(w.w, e.w, a3);
    }
    float e2v = fmaxf(sbd2[j2] + ((a0+a1)+(a2+a3)), 0.f);
    mv = fmaf(swd3m[j2], e2v, mv);
  }
  tab[idx] = mv;
}

// ---------------- proj: 8 rows/block, k-major weights (coalesced lanes = cols) ----------------
__global__ __launch_bounds__(1024) void proj_kernel(const float* __restrict__ lf, const float* __restrict__ pf,
                                                    const float* __restrict__ WlT, const float* __restrict__ bl,
                                                    const float* __restrict__ WpT, const float* __restrict__ bp,
                                                    float* __restrict__ lig, float* __restrict__ poc){
  int b = blockIdx.x, t = threadIdx.x;      // 192 blocks
  bool isLig = (b < 64);
  int r0 = isLig ? b*8 : (b - 64)*8;
  const float* in = (isLig ? lf : pf) + (size_t)r0*HDIM;
  const float* WT = isLig ? WlT : WpT;
  const float* bias = isLig ? bl : bp;
  float* out = (isLig ? lig : poc) + (size_t)r0*HDIM;
  __shared__ float sx[8*HDIM];
  sx[t] = in[t];
  __syncthreads();
  int r = t >> 7, col = t & 127;
  const float* xr = sx + r*HDIM;
  float acc = bias[col];
  #pragma unroll 8
  for (int k = 0; k < 128; k++) acc = fmaf(WT[k*128 + col], xr[k], acc);
  out[r*HDIM + col] = acc;
}

// ---------------- fused agg+gate, 4 rows/block (R7 phases A/B) + k-major gate ----------------
__global__ __launch_bounds__(1024) void agg_gate_fused(const float* __restrict__ lc, const float* __restrict__ pc,
                                                       const float* __restrict__ tab,
                                                       const float* __restrict__ lig, const float* __restrict__ poc,
                                                       const float* __restrict__ WglT, const float* __restrict__ bgl,
                                                       const float* __restrict__ WgpT, const float* __restrict__ bgp,
                                                       float* __restrict__ lenh, float* __restrict__ penh){
  int b = blockIdx.x, t = threadIdx.x;
  bool isLig = (b < NL/4);
  int r0 = isLig ? b*4 : (b - NL/4)*4;
  int n = isLig ? NP : NL;
  const float* myFeat = isLig ? lig : poc;
  const float* otherFeat = isLig ? poc : lig;
  const float* myC = isLig ? lc : pc;
  const float* otC = isLig ? pc : lc;

  __shared__ float w[4*NP];
  __shared__ float sx[4*HDIM];
  __shared__ float sa[4*HDIM];
  __shared__ float part[16*512];
  __shared__ float redm[16];
  __shared__ float sgm[4], sinv[4];

  int rr = t >> 8, u = t & 255;
  int lane = t & 63, wv = t >> 6;
  int row = r0 + rr;

  if (t < 512) sx[t] = myFeat[(size_t)r0*HDIM + t];

  float cx = myC[row*3+0], cy = myC[row*3+1], cz = myC[row*3+2];
  const float inv_h = (float)(TAB_N - 1) / DMAX;
  int per = n >> 8;                  // 4 (lig) or 2 (poc)

  // ---- Phase A: softmax over partners, per row ----
  float xs[4];
  float lmax = -1e30f;
  for (int k = 0; k < per; k++){
    int j = u + (k << 8);
    float ox = otC[j*3+0], oy = otC[j*3+1], oz = otC[j*3+2];
    float dx = cx-ox, dy = cy-oy, dz = cz-oz;
    float d = sqrtf(fmaf(dx,dx, fmaf(dy,dy, dz*dz)));
    float xf = d * inv_h;
    int i0 = (int)xf;
    i0 = (i0 > TAB_N-2) ? (TAB_N-2) : i0;
    float f = xf - (float)i0;
    float v0 = tab[i0], v1 = tab[i0+1];
    xs[k] = -fmaf(f, v1 - v0, v0);
    lmax = fmaxf(lmax, xs[k]);
  }
  float v = lmax;
  #pragma unroll
  for (int off = 32; off; off >>= 1) v = fmaxf(v, __shfl_down(v, off));
  if (lane == 0) redm[wv] = v;
  __syncthreads();
  if (t < 4) sgm[t] = fmaxf(fmaxf(redm[t*4+0], redm[t*4+1]), fmaxf(redm[t*4+2], redm[t*4+3]));
  __syncthreads();
  float gm = sgm[rr];
  float lsum = 0.f;
  for (int k = 0; k < per; k++){
    float e = __expf(xs[k] - gm);
    w[rr*NP + u + (k << 8)] = e;
    lsum += e;
  }
  v = lsum;
  #pragma unroll
  for (int off = 32; off; off >>= 1) v += __shfl_down(v, off);
  if (lane == 0) redm[wv] = v;
  __syncthreads();
  if (t < 4) sinv[t] = 1.0f / ((redm[t*4+0] + redm[t*4+1]) + (redm[t*4+2] + redm[t*4+3]));
  __syncthreads();

  // ---- Phase B: aggregation, 16 j-groups x 2 row-pairs x 32 float4 cols ----
  {
    int jg = t >> 6;
    int rp = (t >> 5) & 1;
    int c4 = t & 31;
    int per2 = n >> 4;               // 64 (lig) / 32 (poc)
    int jb0 = jg * per2;
    int rA = rp*2, rB = rp*2 + 1;
    const float4* of4 = (const float4*)otherFeat;
    const float* wA = w + rA*NP;
    const float* wB = w + rB*NP;
    float4 accA = {0,0,0,0}, accB = {0,0,0,0};
    #pragma unroll 4
    for (int jj = 0; jj < per2; jj++){
      int j = jb0 + jj;
      float4 f = of4[(size_t)j*32 + c4];
      float w0 = wA[j], w1 = wB[j];
      accA.x = fmaf(w0, f.x, accA.x); accA.y = fmaf(w0, f.y, accA.y);
      accA.z = fmaf(w0, f.z, accA.z); accA.w = fmaf(w0, f.w, accA.w);
      accB.x = fmaf(w1, f.x, accB.x); accB.y = fmaf(w1, f.y, accB.y);
      accB.z = fmaf(w1, f.z, accB.z); accB.w = fmaf(w1, f.w, accB.w);
    }
    float4* p4 = (float4*)part;
    p4[jg*128 + rA*32 + c4] = accA;
    p4[jg*128 + rB*32 + c4] = accB;
  }
  __syncthreads();
  {
    float4* p4 = (float4*)part;
    #pragma unroll
    for (int s = 8; s >= 1; s >>= 1){
      if (t < s*128){
        int jg2 = t >> 7, rem = t & 127;
        float4 a = p4[jg2*128 + rem], bb = p4[(jg2+s)*128 + rem];
        a.x += bb.x; a.y += bb.y; a.z += bb.z; a.w += bb.w;
        p4[jg2*128 + rem] = a;
      }
      __syncthreads();
    }
  }
  if (t < 512){
    int r = t >> 7;
    sa[t] = part[t] * sinv[r];
  }
  __syncthreads();

  // ---- Phase C: gate with k-major weights (coalesced lanes = cols) ----
  if (t < 512){
    int r = t >> 7, col = t & 127;
    const float* WT = isLig ? WglT : WgpT;   // [256][128]
    const float* bg = isLig ? bgl : bgp;
    const float* xr = sx + r*HDIM;
    const float* ar = sa + r*HDIM;
    float g = bg[col];
    #pragma unroll 8
    for (int k = 0; k < 128; k++) g = fmaf(WT[k*128 + col], xr[k], g);
    #pragma unroll 8
    for (int k = 0; k < 128; k++) g = fmaf(WT[(128+k)*128 + col], ar[k], g);
    g = 1.0f / (1.0f + __expf(-g));
    float xv = xr[col], av = ar[col];
    float* dst = isLig ? (lenh + (size_t)(r0+r)*HDIM) : (penh + (size_t)(r0+r)*HDIM);
    dst[col] = fmaf(g, xv - av, av);   // g*x + (1-g)*a
  }
}

// ---------------- qkv: 2 rows/block, 768 threads, k-major weights ----------------
__global__ __launch_bounds__(768) void qkv_kernel(const float* __restrict__ lenh, const float* __restrict__ penh,
                                                  const float* __restrict__ WqkvT, const float* __restrict__ bqkv,
                                                  float* __restrict__ qkvl, float* __restrict__ qkvp){
  int b = blockIdx.x, t = threadIdx.x;      // 768 blocks
  int row0 = b*2;
  bool isLig = (row0 < NL);
  int rloc = isLig ? row0 : row0 - NL;
  const float* in = (isLig ? lenh : penh) + (size_t)rloc*HDIM;
  float* out = (isLig ? qkvl : qkvp) + (size_t)rloc*384;
  __shared__ float sx[2*HDIM];
  if (t < 256) sx[t] = in[t];
  __syncthreads();
  int r = (t >= 384) ? 1 : 0;
  int col = t - r*384;
  const float* xr = sx + r*HDIM;
  float acc = bqkv[col];
  #pragma unroll 8
  for (int k = 0; k < 128; k++) acc = fmaf(WqkvT[k*384 + col], xr[k], acc);
  out[r*384 + col] = acc;
}

// ---------------- flash attention (LDS staging, h-major lanes; 2 split-k groups per block) ----------------
__global__ __launch_bounds__(256) void attn_part(const float* __restrict__ qkvl, const float* __restrict__ qkvp,
                                                 float* __restrict__ partL, float* __restrict__ partP){
  int bx = blockIdx.x;
  int t = threadIdx.x;
  const float* qsrc; const float* kvsrc; int qt, slice; bool isLig;
  if (bx < 256){ isLig = true;  qt = bx >> 3; slice = bx & 7; qsrc = qkvl; kvsrc = qkvp; }
  else { int b2 = bx - 256; isLig = false; qt = b2 >> 2; slice = b2 & 3; qsrc = qkvp; kvsrc = qkvl; }
  int g = t >> 7, tt = t & 127;
  int h = tt >> 4, q = tt & 15;
  int j0 = slice*128 + g*64;

  const float4* qp = (const float4*)(qsrc + (size_t)(qt*16+q)*384 + h*16);
  float4 q0 = qp[0], q1 = qp[1], q2 = qp[2], q3 = qp[3];
  float m = -1e30f, l = 0.f;
  float4 O0 = {0,0,0,0}, O1 = {0,0,0,0}, O2 = {0,0,0,0}, O3 = {0,0,0,0};

  __shared__ float sKV[8192];
  float* myKV = sKV + g*4096;

  for (int tile = 0; tile < 4; tile++){
    int jbase = j0 + tile*16;
    __syncthreads();
    #pragma unroll
    for (int n = 0; n < 8; n++){
      int v4 = tt + n*128;
      int jj = v4 >> 6, c4 = v4 & 63;
      ((float4*)myKV)[(size_t)jj*64 + c4] = *(const float4*)(kvsrc + (size_t)(jbase+jj)*384 + 128 + c4*4);
    }
    __syncthreads();
    float s[16];
    #pragma unroll
    for (int jj = 0; jj < 16; jj++){
      const float4* kk = (const float4*)(myKV + jj*256 + h*16);
      s[jj] = (dot4f(q0, kk[0]) + dot4f(q1, kk[1]) + dot4f(q2, kk[2]) + dot4f(q3, kk[3])) * 0.25f;
    }
    float mt = s[0];
    #pragma unroll
    for (int jj = 1; jj < 16; jj++) mt = fmaxf(mt, s[jj]);
    float mn = fmaxf(m, mt);
    float corr = __expf(m - mn);
    l *= corr;
    O0.x*=corr; O0.y*=corr; O0.z*=corr; O0.w*=corr;
    O1.x*=corr; O1.y*=corr; O1.z*=corr; O1.w*=corr;
    O2.x*=corr; O2.y*=corr; O2.z*=corr; O2.w*=corr;
    O3.x*=corr; O3.y*=corr; O3.z*=corr; O3.w*=corr;
    #pragma unroll
    for (int jj = 0; jj < 16; jj++){
      float p = __expf(s[jj] - mn);
      l += p;
      const float4* vv = (const float4*)(myKV + jj*256 + 128 + h*16);
      O0.x = fmaf(p, vv[0].x, O0.x); O0.y = fmaf(p, vv[0].y, O0.y);
      O0.z = fmaf(p, vv[0].z, O0.z); O0.w = fmaf(p, vv[0].w, O0.w);
      O1.x = fmaf(p, vv[1].x, O1.x); O1.y = fmaf(p, vv[1].y, O1.y);
      O1.z = fmaf(p, vv[1].z, O1.z); O1.w = fmaf(p, vv[1].w, O1.w);
      O2.x = fmaf(p, vv[2].x, O2.x); O2.y = fmaf(p, vv[2].y, O2.y);
      O2.z = fmaf(p, vv[2].z, O2.z); O2.w = fmaf(p, vv[2].w, O2.w);
      O3.x = fmaf(p, vv[3].x, O3.x); O3.y = fmaf(p, vv[3].y, O3.y);
      O3.z = fmaf(p, vv[3].z, O3.z); O3.w = fmaf(p, vv[3].w, O3.w);
    }
    m = mn;
  }

  __syncthreads();
  float* smerge = sKV;
  if (g == 1){
    float* b = smerge + tt*19;
    b[0] = m; b[1] = l;
    b[2]=O0.x; b[3]=O0.y; b[4]=O0.z; b[5]=O0.w;
    b[6]=O1.x; b[7]=O1.y; b[8]=O1.z; b[9]=O1.w;
    b[10]=O2.x; b[11]=O2.y; b[12]=O2.z; b[13]=O2.w;
    b[14]=O3.x; b[15]=O3.y; b[16]=O3.z; b[17]=O3.w;
  }
  __syncthreads();
  if (g == 0){
    const float* b = smerge + tt*19;
    float m1 = b[0], l1 = b[1];
    float M = fmaxf(m, m1);
    float e0 = __expf(m - M), e1 = __expf(m1 - M);
    float L = l*e0 + l1*e1;
    float* dst;
    if (isLig) dst = partL + ((size_t)((qt*16+q)*8 + h)*8 + slice)*18;
    else       dst = partP + ((size_t)((qt*16+q)*8 + h)*4 + slice)*18;
    dst[0] = M; dst[1] = L;
    dst[2]  = O0.x*e0 + b[2]*e1;  dst[3]  = O0.y*e0 + b[3]*e1;
    dst[4]  = O0.z*e0 + b[4]*e1;  dst[5]  = O0.w*e0 + b[5]*e1;
    dst[6]  = O1.x*e0 + b[6]*e1;  dst[7]  = O1.y*e0 + b[7]*e1;
    dst[8]  = O1.z*e0 + b[8]*e1;  dst[9]  = O1.w*e0 + b[9]*e1;
    dst[10] = O2.x*e0 + b[10]*e1; dst[11] = O2.y*e0 + b[11]*e1;
    dst[12] = O2.z*e0 + b[12]*e1; dst[13] = O2.w*e0 + b[13]*e1;
    dst[14] = O3.x*e0 + b[14]*e1; dst[15] = O3.y*e0 + b[15]*e1;
    dst[16] = O3.z*e0 + b[16]*e1; dst[17] = O3.w*e0 + b[17]*e1;
  }
}

// ---------------- merge partials + Wo proj (k-major) + residual + LayerNorm; 8 rows/block ----------------
__global__ __launch_bounds__(1024) void merge_ln(const float* __restrict__ partL, const float* __restrict__ partP,
                                                 const float* __restrict__ lenh, const float* __restrict__ penh,
                                                 const float* __restrict__ WoT, const float* __restrict__ bo,
                                                 const float* __restrict__ g_l, const float* __restrict__ be_l,
                                                 const float* __restrict__ g_p, const float* __restrict__ be_p,
                                                 float* __restrict__ out){
  int b = blockIdx.x, t = threadIdx.x;      // 192 blocks
  int r0 = b*8;
  int r = t >> 7, c = t & 127;
  int gr = r0 + r;
  int h = c >> 4, cc = c & 15;
  int ns; const float* base;
  if (gr < NL){ ns = 8; base = partL + ((size_t)(gr*8 + h))*8*18; }
  else        { ns = 4; base = partP + ((size_t)((gr-NL)*8 + h))*4*18; }
  float M = -1e30f;
  for (int s = 0; s < ns; s++) M = fmaxf(M, base[s*18]);
  float Lsum = 0.f, Osum = 0.f;
  for (int s = 0; s < ns; s++){
    float e = __expf(base[s*18] - M);
    Lsum = fmaf(e, base[s*18+1], Lsum);
    Osum = fmaf(e, base[s*18+2+cc], Osum);
  }
  __shared__ float sAtt[8*HDIM];
  sAtt[t] = Osum / Lsum;
  __syncthreads();
  float o = bo[c];
  const float* sA = sAtt + r*HDIM;
  #pragma unroll 8
  for (int k = 0; k < 128; k++) o = fmaf(WoT[k*128 + c], sA[k], o);
  const float* enh = (gr < NL) ? (lenh + (size_t)gr*HDIM) : (penh + (size_t)(gr-NL)*HDIM);
  float x = enh[c] + o;
  // LayerNorm across the 128 threads of row r (2 waves)
  __shared__ float sred[32];
  int wid = t >> 6;
  float v = x;
  #pragma unroll
  for (int off = 32; off; off >>= 1) v += __shfl_down(v, off);
  if ((t & 63) == 0) sred[wid] = v;
  __syncthreads();
  float mu = (sred[2*r] + sred[2*r+1]) * (1.f/128.f);
  float dx = x - mu;
  v = dx*dx;
  #pragma unroll
  for (int off = 32; off; off >>= 1) v += __shfl_down(v, off);
  if ((t & 63) == 0) sred[16 + wid] = v;
  __syncthreads();
  float var = (sred[16 + 2*r] + sred[16 + 2*r+1]) * (1.f/128.f);
  float y = dx * rsqrtf(var + 1e-5f);
  if (gr < NL) y = fmaf(y, g_l[c], be_l[c]);
  else         y = fmaf(y, g_p[c], be_p[c]);
  out[(size_t)gr*HDIM + c] = y;
}

extern "C" void kernel_launch(void* const* d_in, const int* in_sizes, int n_in,
                              void* d_out, int out_size, void* d_ws, size_t ws_size,
                              hipStream_t stream){
  const float* lf   = (const float*)d_in[0];
  const float* pf   = (const float*)d_in[1];
  const float* lc   = (const float*)d_in[2];
  const float* pc   = (const float*)d_in[3];
  const float* Wl   = (const float*)d_in[4];
  const float* bl   = (const float*)d_in[5];
  const float* Wp   = (const float*)d_in[6];
  const float* bp   = (const float*)d_in[7];
  const float* Wd1  = (const float*)d_in[8];
  const float* bd1  = (const float*)d_in[9];
  const float* Wd2  = (const float*)d_in[10];
  const float* bd2  = (const float*)d_in[11];
  const float* Wd3  = (const float*)d_in[12];
  const float* bd3  = (const float*)d_in[13];
  const float* Wgl  = (const float*)d_in[14];
  const float* bgl  = (const float*)d_in[15];
  const float* Wgp  = (const float*)d_in[16];
  const float* bgp  = (const float*)d_in[17];
  const float* Wqkv = (const float*)d_in[18];
  const float* bqkv = (const float*)d_in[19];
  const float* Wo   = (const float*)d_in[20];
  const float* bo   = (const float*)d_in[21];
  const float* g_l  = (const float*)d_in[22];
  const float* be_l = (const float*)d_in[23];
  const float* g_p  = (const float*)d_in[24];
  const float* be_p = (const float*)d_in[25];

  float* ws  = (float*)d_ws;
  float* out = (float*)d_out;
  float* lig   = ws + LIG_OFF;
  float* poc   = ws + POC_OFF;
  float* lenh  = ws + LENH_OFF;
  float* penh  = ws + PENH_OFF;
  float* qkvl  = ws + QKVL_OFF;
  float* qkvp  = ws + QKVP_OFF;
  float* partL = ws + PARTL_OFF;
  float* partP = ws + PARTP_OFF;
  float* tab   = ws + TAB_OFF;   // aliases qkvl region; consumed before qkv_kernel writes

  transpose_all<<<160, 256, 0, stream>>>(Wl, Wp, Wqkv, Wo, Wgl, Wgp, ws);
  table_kernel<<<TAB_N/256, 256, 0, stream>>>(Wd1, bd1, Wd2, bd2, Wd3, bd3, tab);
  proj_kernel<<<192, 1024, 0, stream>>>(lf, pf, ws + WLT_OFF, bl, ws + WPT_OFF, bp, lig, poc);
  agg_gate_fused<<<NL/4 + NP/4, 1024, 0, stream>>>(lc, pc, tab, lig, poc,
                                                   ws + WGLT_OFF, bgl, ws + WGPT_OFF, bgp, lenh, penh);
  qkv_kernel<<<768, 768, 0, stream>>>(lenh, penh, ws + WQT_OFF, bqkv, qkvl, qkvp);
  attn_part<<<512, 256, 0, stream>>>(qkvl, qkvp, partL, partP);
  merge_ln<<<192, 1024, 0, stream>>>(partL, partP, lenh, penh, ws + WOT_OFF, bo,
                                     g_l, be_l, g_p, be_p, out);
}

// Round 11
// 198.056 us; speedup vs baseline: 1.2389x; 1.0571x over previous
//
#include <hip/hip_runtime.h>
#include <math.h>

#define NL 512
#define NP 1024
#define HDIM 128

#define TAB_N 8192
#define DMAX 34.65f

// ---- workspace layout (float offsets) ----
#define M_OFF    128
#define WLT_OFF  (M_OFF)                      // WlT  [128][128]
#define WPT_OFF  (M_OFF + 16384)              // WpT  [128][128]
#define WQT_OFF  (M_OFF + 32768)              // WqkvT[128][384]
#define WOT_OFF  (M_OFF + 81920)              // WoT  [128][128]
#define WGLT_OFF (M_OFF + 98304)              // WglT [256][128]
#define WGPT_OFF (M_OFF + 131072)             // WgpT [256][128]
#define TAB_OFF  (M_OFF + 163840)             // m(d) table
#define LIG_OFF  (M_OFF + NL*NP)              // lig proj 512x128
#define POC_OFF  (LIG_OFF + NL*HDIM)          // poc proj 1024x128
#define LENH_OFF (POC_OFF + NP*HDIM)          // lig_enh 512x128
#define PENH_OFF (LENH_OFF + NL*HDIM)         // poc_enh 1024x128
#define QKVL_OFF (PENH_OFF + NP*HDIM)         // qkv for lig_enh 512x384
#define QKVP_OFF (QKVL_OFF + NL*384)          // qkv for poc_enh 1024x384
#define PARTL_OFF (QKVP_OFF + NP*384)         // lig partials: [512][8 h][8 slices][18]
#define PARTP_OFF (PARTL_OFF + 512*8*8*18)    // poc partials: [1024][8 h][4 slices][18]

__device__ __forceinline__ float dot4f(float4 a, float4 b){
  return fmaf(a.x,b.x, fmaf(a.y,b.y, fmaf(a.z,b.z, a.w*b.w)));
}

// ---------------- prep: transpose all matvec weights + build m(d) LUT (one kernel) ----------------
__device__ __forceinline__ void tpose(const float* __restrict__ src, float* __restrict__ dst,
                                      int O, int K, int blk0, int t){
  int e0 = blk0*1024 + t*4;
  #pragma unroll
  for (int i = 0; i < 4; i++){
    int e = e0 + i;
    int o = e / K, k = e - o*K;
    dst[(size_t)k*O + o] = src[(size_t)o*K + k];
  }
}
__global__ __launch_bounds__(256) void prep_all(const float* __restrict__ Wl, const float* __restrict__ Wp,
                                                const float* __restrict__ Wqkv, const float* __restrict__ Wo,
                                                const float* __restrict__ Wgl, const float* __restrict__ Wgp,
                                                const float* __restrict__ Wd1, const float* __restrict__ bd1,
                                                const float* __restrict__ Wd2, const float* __restrict__ bd2,
                                                const float* __restrict__ Wd3, const float* __restrict__ bd3,
                                                float* __restrict__ ws){
  int b = blockIdx.x, t = threadIdx.x;
  if (b < 160){
    if      (b < 16)  tpose(Wl,   ws + WLT_OFF,  128, 128, b,       t);
    else if (b < 32)  tpose(Wp,   ws + WPT_OFF,  128, 128, b - 16,  t);
    else if (b < 80)  tpose(Wqkv, ws + WQT_OFF,  384, 128, b - 32,  t);
    else if (b < 96)  tpose(Wo,   ws + WOT_OFF,  128, 128, b - 80,  t);
    else if (b < 128) tpose(Wgl,  ws + WGLT_OFF, 128, 256, b - 96,  t);
    else              tpose(Wgp,  ws + WGPT_OFF, 128, 256, b - 128, t);
    return;
  }
  // table part: blocks 160..191
  float* tab = ws + TAB_OFF;
  __shared__ float sWd1[32], sbd1[32], sWd2[2048], sbd2[64], swd3m[64];
  __shared__ float sbd3m;
  int idx = (b - 160) * 256 + t;
  if (t < 64){
    float s = 0.f;
    #pragma unroll 8
    for (int i = 0; i < 128; i++) s += Wd3[i*64 + t];
    swd3m[t] = s * (1.f/128.f);
  } else if (t == 64){
    float s = 0.f;
    for (int i = 0; i < 128; i++) s += bd3[i];
    sbd3m = s * (1.f/128.f);
  } else if (t >= 128 && t < 160){ sWd1[t-128] = Wd1[t-128]; sbd1[t-128] = bd1[t-128]; }
  else if (t >= 160 && t < 224){ sbd2[t-160] = bd2[t-160]; }
  for (int k = t; k < 2048; k += 256) sWd2[k] = Wd2[k];
  __syncthreads();

  float d = (float)idx * (DMAX / (float)(TAB_N - 1));
  float4 e1q[8];
  const float4* w1q = (const float4*)sWd1;
  const float4* b1q = (const float4*)sbd1;
  #pragma unroll
  for (int k4 = 0; k4 < 8; k4++){
    float4 w = w1q[k4], bb = b1q[k4];
    float4 e;
    e.x = fmaxf(fmaf(d, w.x, bb.x), 0.f);
    e.y = fmaxf(fmaf(d, w.y, bb.y), 0.f);
    e.z = fmaxf(fmaf(d, w.z, bb.z), 0.f);
    e.w = fmaxf(fmaf(d, w.w, bb.w), 0.f);
    e1q[k4] = e;
  }
  float mv = sbd3m;
  #pragma unroll 4
  for (int j2 = 0; j2 < 64; j2++){
    const float4* wrow = (const float4*)(sWd2 + j2*32);
    float a0 = 0.f, a1 = 0.f, a2 = 0.f, a3 = 0.f;
    #pragma unroll
    for (int k4 = 0; k4 < 8; k4++){
      float4 w = wrow[k4], e = e1q[k4];
      a0 = fmaf(w.x, e.x, a0);
      a1 = fmaf(w.y, e.y, a1);
      a2 = fmaf(w.z, e.z, a2);
      a3 = fmaf(w.w, e.w, a3);
    }
    float e2v = fmaxf(sbd2[j2] + ((a0+a1)+(a2+a3)), 0.f);
    mv = fmaf(swd3m[j2], e2v, mv);
  }
  tab[idx] = mv;
}

// ---------------- proj: 8 rows/block, k-major weights ----------------
__global__ __launch_bounds__(1024) void proj_kernel(const float* __restrict__ lf, const float* __restrict__ pf,
                                                    const float* __restrict__ WlT, const float* __restrict__ bl,
                                                    const float* __restrict__ WpT, const float* __restrict__ bp,
                                                    float* __restrict__ lig, float* __restrict__ poc){
  int b = blockIdx.x, t = threadIdx.x;      // 192 blocks
  bool isLig = (b < 64);
  int r0 = isLig ? b*8 : (b - 64)*8;
  const float* in = (isLig ? lf : pf) + (size_t)r0*HDIM;
  const float* WT = isLig ? WlT : WpT;
  const float* bias = isLig ? bl : bp;
  float* out = (isLig ? lig : poc) + (size_t)r0*HDIM;
  __shared__ float sx[8*HDIM];
  sx[t] = in[t];
  __syncthreads();
  int r = t >> 7, col = t & 127;
  const float* xr = sx + r*HDIM;
  float acc = bias[col];
  #pragma unroll 8
  for (int k = 0; k < 128; k++) acc = fmaf(WT[k*128 + col], xr[k], acc);
  out[r*HDIM + col] = acc;
}

// ---------------- fused agg+gate+QKV, 4 rows/block (race-fixed) ----------------
__global__ __launch_bounds__(1024) void agg_gate_fused(const float* __restrict__ lc, const float* __restrict__ pc,
                                                       const float* __restrict__ tab,
                                                       const float* __restrict__ lig, const float* __restrict__ poc,
                                                       const float* __restrict__ WglT, const float* __restrict__ bgl,
                                                       const float* __restrict__ WgpT, const float* __restrict__ bgp,
                                                       const float* __restrict__ WqkvT, const float* __restrict__ bqkv,
                                                       float* __restrict__ lenh, float* __restrict__ penh,
                                                       float* __restrict__ qkvl, float* __restrict__ qkvp){
  int b = blockIdx.x, t = threadIdx.x;
  bool isLig = (b < NL/4);
  int r0 = isLig ? b*4 : (b - NL/4)*4;
  int n = isLig ? NP : NL;
  const float* myFeat = isLig ? lig : poc;
  const float* otherFeat = isLig ? poc : lig;
  const float* myC = isLig ? lc : pc;
  const float* otC = isLig ? pc : lc;

  __shared__ float w[4*NP];
  __shared__ float sx[4*HDIM];
  __shared__ float sa[4*HDIM];
  __shared__ float part[16*512];
  __shared__ float redm[16];
  __shared__ float sgm[4], sinv[4];

  int rr = t >> 8, u = t & 255;
  int lane = t & 63, wv = t >> 6;
  int row = r0 + rr;

  if (t < 512) sx[t] = myFeat[(size_t)r0*HDIM + t];

  float cx = myC[row*3+0], cy = myC[row*3+1], cz = myC[row*3+2];
  const float inv_h = (float)(TAB_N - 1) / DMAX;
  int per = n >> 8;                  // 4 (lig) or 2 (poc)

  // ---- Phase A: softmax over partners, per row ----
  float xs[4];
  float lmax = -1e30f;
  for (int k = 0; k < per; k++){
    int j = u + (k << 8);
    float ox = otC[j*3+0], oy = otC[j*3+1], oz = otC[j*3+2];
    float dx = cx-ox, dy = cy-oy, dz = cz-oz;
    float d = sqrtf(fmaf(dx,dx, fmaf(dy,dy, dz*dz)));
    float xf = d * inv_h;
    int i0 = (int)xf;
    i0 = (i0 > TAB_N-2) ? (TAB_N-2) : i0;
    float f = xf - (float)i0;
    float v0 = tab[i0], v1 = tab[i0+1];
    xs[k] = -fmaf(f, v1 - v0, v0);
    lmax = fmaxf(lmax, xs[k]);
  }
  float v = lmax;
  #pragma unroll
  for (int off = 32; off; off >>= 1) v = fmaxf(v, __shfl_down(v, off));
  if (lane == 0) redm[wv] = v;
  __syncthreads();
  if (t < 4) sgm[t] = fmaxf(fmaxf(redm[t*4+0], redm[t*4+1]), fmaxf(redm[t*4+2], redm[t*4+3]));
  __syncthreads();
  float gm = sgm[rr];
  float lsum = 0.f;
  for (int k = 0; k < per; k++){
    float e = __expf(xs[k] - gm);
    w[rr*NP + u + (k << 8)] = e;
    lsum += e;
  }
  v = lsum;
  #pragma unroll
  for (int off = 32; off; off >>= 1) v += __shfl_down(v, off);
  if (lane == 0) redm[wv] = v;
  __syncthreads();
  if (t < 4) sinv[t] = 1.0f / ((redm[t*4+0] + redm[t*4+1]) + (redm[t*4+2] + redm[t*4+3]));
  __syncthreads();

  // ---- Phase B: aggregation, 16 j-groups x 2 row-pairs x 32 float4 cols ----
  {
    int jg = t >> 6;
    int rp = (t >> 5) & 1;
    int c4 = t & 31;
    int per2 = n >> 4;               // 64 (lig) / 32 (poc)
    int jb0 = jg * per2;
    int rA = rp*2, rB = rp*2 + 1;
    const float4* of4 = (const float4*)otherFeat;
    const float* wA = w + rA*NP;
    const float* wB = w + rB*NP;
    float4 accA = {0,0,0,0}, accB = {0,0,0,0};
    #pragma unroll 4
    for (int jj = 0; jj < per2; jj++){
      int j = jb0 + jj;
      float4 f = of4[(size_t)j*32 + c4];
      float w0 = wA[j], w1 = wB[j];
      accA.x = fmaf(w0, f.x, accA.x); accA.y = fmaf(w0, f.y, accA.y);
      accA.z = fmaf(w0, f.z, accA.z); accA.w = fmaf(w0, f.w, accA.w);
      accB.x = fmaf(w1, f.x, accB.x); accB.y = fmaf(w1, f.y, accB.y);
      accB.z = fmaf(w1, f.z, accB.z); accB.w = fmaf(w1, f.w, accB.w);
    }
    float4* p4 = (float4*)part;
    p4[jg*128 + rA*32 + c4] = accA;
    p4[jg*128 + rB*32 + c4] = accB;
  }
  __syncthreads();
  {
    float4* p4 = (float4*)part;
    #pragma unroll
    for (int s = 8; s >= 1; s >>= 1){
      if (t < s*128){
        int jg2 = t >> 7, rem = t & 127;
        float4 a = p4[jg2*128 + rem], bb = p4[(jg2+s)*128 + rem];
        a.x += bb.x; a.y += bb.y; a.z += bb.z; a.w += bb.w;
        p4[jg2*128 + rem] = a;
      }
      __syncthreads();
    }
  }
  if (t < 512){
    int r = t >> 7;
    sa[t] = part[t] * sinv[r];
  }
  __syncthreads();

  // ---- Phase C: gate (k-major). Keep enh in a REGISTER; publish to LDS only after a barrier
  //      (writing sa during the gate loop raced with other threads' reads — R10 bug). ----
  float enh_val = 0.f;
  {
    if (t < 512){
      int r = t >> 7, col = t & 127;
      const float* WT = isLig ? WglT : WgpT;   // [256][128]
      const float* bg = isLig ? bgl : bgp;
      const float* xr = sx + r*HDIM;
      const float* ar = sa + r*HDIM;
      float g = bg[col];
      #pragma unroll 8
      for (int k = 0; k < 128; k++) g = fmaf(WT[k*128 + col], xr[k], g);
      #pragma unroll 8
      for (int k = 0; k < 128; k++) g = fmaf(WT[(128+k)*128 + col], ar[k], g);
      g = 1.0f / (1.0f + __expf(-g));
      float xv = xr[col], av = ar[col];
      enh_val = fmaf(g, xv - av, av);   // g*x + (1-g)*a
      float* dst = isLig ? (lenh + (size_t)(r0+r)*HDIM) : (penh + (size_t)(r0+r)*HDIM);
      dst[col] = enh_val;
    }
  }
  __syncthreads();                      // all gate reads of sa complete
  if (t < 512) sa[t] = enh_val;         // now safe to overwrite sa with enh rows
  __syncthreads();

  // ---- Phase D: QKV projection for these 4 rows (k-major, 3 cols/thread) ----
  if (t < 512){
    int r = t >> 7, c0 = t & 127;
    const float* er = sa + r*HDIM;
    float acc0 = bqkv[c0], acc1 = bqkv[c0+128], acc2 = bqkv[c0+256];
    #pragma unroll 4
    for (int k = 0; k < 128; k++){
      float xv = er[k];
      const float* wk = WqkvT + k*384;
      acc0 = fmaf(wk[c0],       xv, acc0);
      acc1 = fmaf(wk[c0+128],   xv, acc1);
      acc2 = fmaf(wk[c0+256],   xv, acc2);
    }
    float* qout = (isLig ? qkvl : qkvp) + (size_t)(r0+r)*384;
    qout[c0] = acc0; qout[c0+128] = acc1; qout[c0+256] = acc2;
  }
}

// ---------------- flash attention: 2 queries/thread, 4 split-k groups, 8-key tiles ----------------
__global__ __launch_bounds__(256) void attn_part(const float* __restrict__ qkvl, const float* __restrict__ qkvp,
                                                 float* __restrict__ partL, float* __restrict__ partP){
  int bx = blockIdx.x;
  int t = threadIdx.x;
  const float* qsrc; const float* kvsrc; int qt, slice; bool isLig;
  if (bx < 256){ isLig = true;  qt = bx >> 3; slice = bx & 7; qsrc = qkvl; kvsrc = qkvp; }
  else { int b2 = bx - 256; isLig = false; qt = b2 >> 2; slice = b2 & 3; qsrc = qkvp; kvsrc = qkvl; }
  int g = t >> 6, tt = t & 63;
  int h = tt >> 3, qp = tt & 7;
  int j0 = slice*128 + g*32;

  const float4* qA = (const float4*)(qsrc + (size_t)(qt*16+qp)*384 + h*16);
  const float4* qB = (const float4*)(qsrc + (size_t)(qt*16+qp+8)*384 + h*16);
  float4 a0 = qA[0], a1 = qA[1], a2 = qA[2], a3 = qA[3];
  float4 b0 = qB[0], b1 = qB[1], b2 = qB[2], b3 = qB[3];
  float mA = -1e30f, lA = 0.f, mB = -1e30f, lB = 0.f;
  float4 OA0={0,0,0,0}, OA1={0,0,0,0}, OA2={0,0,0,0}, OA3={0,0,0,0};
  float4 OB0={0,0,0,0}, OB1={0,0,0,0}, OB2={0,0,0,0}, OB3={0,0,0,0};

  __shared__ float sKV[8192];          // 4 groups x 8 keys x 256 floats = 32 KB
  float* myKV = sKV + g*2048;

  for (int tile = 0; tile < 4; tile++){
    int jbase = j0 + tile*8;
    __syncthreads();
    #pragma unroll
    for (int nn = 0; nn < 8; nn++){
      int v4 = tt + nn*64;             // 512 float4 per group
      int jj = v4 >> 6, c4 = v4 & 63;
      ((float4*)myKV)[jj*64 + c4] = *(const float4*)(kvsrc + (size_t)(jbase+jj)*384 + 128 + c4*4);
    }
    __syncthreads();
    float sA[8], sB[8];
    #pragma unroll
    for (int jj = 0; jj < 8; jj++){
      const float4* kk = (const float4*)(myKV + jj*256 + h*16);
      float4 k0 = kk[0], k1 = kk[1], k2 = kk[2], k3 = kk[3];
      sA[jj] = (dot4f(a0,k0) + dot4f(a1,k1) + dot4f(a2,k2) + dot4f(a3,k3)) * 0.25f;
      sB[jj] = (dot4f(b0,k0) + dot4f(b1,k1) + dot4f(b2,k2) + dot4f(b3,k3)) * 0.25f;
    }
    float mtA = sA[0], mtB = sB[0];
    #pragma unroll
    for (int jj = 1; jj < 8; jj++){ mtA = fmaxf(mtA, sA[jj]); mtB = fmaxf(mtB, sB[jj]); }
    float mnA = fmaxf(mA, mtA), mnB = fmaxf(mB, mtB);
    float cA = __expf(mA - mnA), cB = __expf(mB - mnB);
    lA *= cA; lB *= cB;
    OA0.x*=cA; OA0.y*=cA; OA0.z*=cA; OA0.w*=cA;
    OA1.x*=cA; OA1.y*=cA; OA1.z*=cA; OA1.w*=cA;
    OA2.x*=cA; OA2.y*=cA; OA2.z*=cA; OA2.w*=cA;
    OA3.x*=cA; OA3.y*=cA; OA3.z*=cA; OA3.w*=cA;
    OB0.x*=cB; OB0.y*=cB; OB0.z*=cB; OB0.w*=cB;
    OB1.x*=cB; OB1.y*=cB; OB1.z*=cB; OB1.w*=cB;
    OB2.x*=cB; OB2.y*=cB; OB2.z*=cB; OB2.w*=cB;
    OB3.x*=cB; OB3.y*=cB; OB3.z*=cB; OB3.w*=cB;
    #pragma unroll
    for (int jj = 0; jj < 8; jj++){
      float pA = __expf(sA[jj] - mnA);
      float pB = __expf(sB[jj] - mnB);
      lA += pA; lB += pB;
      const float4* vv = (const float4*)(myKV + jj*256 + 128 + h*16);
      float4 v0 = vv[0], v1 = vv[1], v2 = vv[2], v3 = vv[3];
      OA0.x = fmaf(pA, v0.x, OA0.x); OA0.y = fmaf(pA, v0.y, OA0.y);
      OA0.z = fmaf(pA, v0.z, OA0.z); OA0.w = fmaf(pA, v0.w, OA0.w);
      OA1.x = fmaf(pA, v1.x, OA1.x); OA1.y = fmaf(pA, v1.y, OA1.y);
      OA1.z = fmaf(pA, v1.z, OA1.z); OA1.w = fmaf(pA, v1.w, OA1.w);
      OA2.x = fmaf(pA, v2.x, OA2.x); OA2.y = fmaf(pA, v2.y, OA2.y);
      OA2.z = fmaf(pA, v2.z, OA2.z); OA2.w = fmaf(pA, v2.w, OA2.w);
      OA3.x = fmaf(pA, v3.x, OA3.x); OA3.y = fmaf(pA, v3.y, OA3.y);
      OA3.z = fmaf(pA, v3.z, OA3.z); OA3.w = fmaf(pA, v3.w, OA3.w);
      OB0.x = fmaf(pB, v0.x, OB0.x); OB0.y = fmaf(pB, v0.y, OB0.y);
      OB0.z = fmaf(pB, v0.z, OB0.z); OB0.w = fmaf(pB, v0.w, OB0.w);
      OB1.x = fmaf(pB, v1.x, OB1.x); OB1.y = fmaf(pB, v1.y, OB1.y);
      OB1.z = fmaf(pB, v1.z, OB1.z); OB1.w = fmaf(pB, v1.w, OB1.w);
      OB2.x = fmaf(pB, v2.x, OB2.x); OB2.y = fmaf(pB, v2.y, OB2.y);
      OB2.z = fmaf(pB, v2.z, OB2.z); OB2.w = fmaf(pB, v2.w, OB2.w);
      OB3.x = fmaf(pB, v3.x, OB3.x); OB3.y = fmaf(pB, v3.y, OB3.y);
      OB3.z = fmaf(pB, v3.z, OB3.z); OB3.w = fmaf(pB, v3.w, OB3.w);
    }
    mA = mnA; mB = mnB;
  }

  // ---- merge the 4 split-k groups via LDS (groups 1..3 publish; group 0 merges) ----
  __syncthreads();
  if (g > 0){
    float* bA = sKV + (size_t)((g-1)*128 + tt*2)*19;
    bA[0]=mA; bA[1]=lA;
    bA[2]=OA0.x; bA[3]=OA0.y; bA[4]=OA0.z; bA[5]=OA0.w;
    bA[6]=OA1.x; bA[7]=OA1.y; bA[8]=OA1.z; bA[9]=OA1.w;
    bA[10]=OA2.x; bA[11]=OA2.y; bA[12]=OA2.z; bA[13]=OA2.w;
    bA[14]=OA3.x; bA[15]=OA3.y; bA[16]=OA3.z; bA[17]=OA3.w;
    float* bB = bA + 19;
    bB[0]=mB; bB[1]=lB;
    bB[2]=OB0.x; bB[3]=OB0.y; bB[4]=OB0.z; bB[5]=OB0.w;
    bB[6]=OB1.x; bB[7]=OB1.y; bB[8]=OB1.z; bB[9]=OB1.w;
    bB[10]=OB2.x; bB[11]=OB2.y; bB[12]=OB2.z; bB[13]=OB2.w;
    bB[14]=OB3.x; bB[15]=OB3.y; bB[16]=OB3.z; bB[17]=OB3.w;
  }
  __syncthreads();
  if (g == 0){
    float M = mA, L = lA;
    float O[16] = {OA0.x,OA0.y,OA0.z,OA0.w, OA1.x,OA1.y,OA1.z,OA1.w,
                   OA2.x,OA2.y,OA2.z,OA2.w, OA3.x,OA3.y,OA3.z,OA3.w};
    #pragma unroll
    for (int gg = 1; gg < 4; gg++){
      const float* br = sKV + (size_t)((gg-1)*128 + tt*2)*19;
      float m1 = br[0], l1 = br[1];
      float Mn = fmaxf(M, m1);
      float e0 = __expf(M - Mn), e1 = __expf(m1 - Mn);
      L = L*e0 + l1*e1;
      #pragma unroll
      for (int k = 0; k < 16; k++) O[k] = O[k]*e0 + br[2+k]*e1;
      M = Mn;
    }
    int rowA = qt*16 + qp;
    float* dst = isLig ? (partL + ((size_t)(rowA*8 + h)*8 + slice)*18)
                       : (partP + ((size_t)(rowA*8 + h)*4 + slice)*18);
    dst[0] = M; dst[1] = L;
    #pragma unroll
    for (int k = 0; k < 16; k++) dst[2+k] = O[k];
    M = mB; L = lB;
    float Ob[16] = {OB0.x,OB0.y,OB0.z,OB0.w, OB1.x,OB1.y,OB1.z,OB1.w,
                    OB2.x,OB2.y,OB2.z,OB2.w, OB3.x,OB3.y,OB3.z,OB3.w};
    #pragma unroll
    for (int gg = 1; gg < 4; gg++){
      const float* br = sKV + (size_t)((gg-1)*128 + tt*2 + 1)*19;
      float m1 = br[0], l1 = br[1];
      float Mn = fmaxf(M, m1);
      float e0 = __expf(M - Mn), e1 = __expf(m1 - Mn);
      L = L*e0 + l1*e1;
      #pragma unroll
      for (int k = 0; k < 16; k++) Ob[k] = Ob[k]*e0 + br[2+k]*e1;
      M = Mn;
    }
    int rowB = qt*16 + qp + 8;
    float* dstB = isLig ? (partL + ((size_t)(rowB*8 + h)*8 + slice)*18)
                        : (partP + ((size_t)(rowB*8 + h)*4 + slice)*18);
    dstB[0] = M; dstB[1] = L;
    #pragma unroll
    for (int k = 0; k < 16; k++) dstB[2+k] = Ob[k];
  }
}

// ---------------- merge partials + Wo proj (k-major) + residual + LayerNorm; 8 rows/block ----------------
__global__ __launch_bounds__(1024) void merge_ln(const float* __restrict__ partL, const float* __restrict__ partP,
                                                 const float* __restrict__ lenh, const float* __restrict__ penh,
                                                 const float* __restrict__ WoT, const float* __restrict__ bo,
                                                 const float* __restrict__ g_l, const float* __restrict__ be_l,
                                                 const float* __restrict__ g_p, const float* __restrict__ be_p,
                                                 float* __restrict__ out){
  int b = blockIdx.x, t = threadIdx.x;      // 192 blocks
  int r0 = b*8;
  int r = t >> 7, c = t & 127;
  int gr = r0 + r;
  int h = c >> 4, cc = c & 15;
  int ns; const float* base;
  if (gr < NL){ ns = 8; base = partL + ((size_t)(gr*8 + h))*8*18; }
  else        { ns = 4; base = partP + ((size_t)((gr-NL)*8 + h))*4*18; }
  float M = -1e30f;
  for (int s = 0; s < ns; s++) M = fmaxf(M, base[s*18]);
  float Lsum = 0.f, Osum = 0.f;
  for (int s = 0; s < ns; s++){
    float e = __expf(base[s*18] - M);
    Lsum = fmaf(e, base[s*18+1], Lsum);
    Osum = fmaf(e, base[s*18+2+cc], Osum);
  }
  __shared__ float sAtt[8*HDIM];
  sAtt[t] = Osum / Lsum;
  __syncthreads();
  float o = bo[c];
  const float* sA = sAtt + r*HDIM;
  #pragma unroll 8
  for (int k = 0; k < 128; k++) o = fmaf(WoT[k*128 + c], sA[k], o);
  const float* enh = (gr < NL) ? (lenh + (size_t)gr*HDIM) : (penh + (size_t)(gr-NL)*HDIM);
  float x = enh[c] + o;
  __shared__ float sred[32];
  int wid = t >> 6;
  float v = x;
  #pragma unroll
  for (int off = 32; off; off >>= 1) v += __shfl_down(v, off);
  if ((t & 63) == 0) sred[wid] = v;
  __syncthreads();
  float mu = (sred[2*r] + sred[2*r+1]) * (1.f/128.f);
  float dx = x - mu;
  v = dx*dx;
  #pragma unroll
  for (int off = 32; off; off >>= 1) v += __shfl_down(v, off);
  if ((t & 63) == 0) sred[16 + wid] = v;
  __syncthreads();
  float var = (sred[16 + 2*r] + sred[16 + 2*r+1]) * (1.f/128.f);
  float y = dx * rsqrtf(var + 1e-5f);
  if (gr < NL) y = fmaf(y, g_l[c], be_l[c]);
  else         y = fmaf(y, g_p[c], be_p[c]);
  out[(size_t)gr*HDIM + c] = y;
}

extern "C" void kernel_launch(void* const* d_in, const int* in_sizes, int n_in,
                              void* d_out, int out_size, void* d_ws, size_t ws_size,
                              hipStream_t stream){
  const float* lf   = (const float*)d_in[0];
  const float* pf   = (const float*)d_in[1];
  const float* lc   = (const float*)d_in[2];
  const float* pc   = (const float*)d_in[3];
  const float* Wl   = (const float*)d_in[4];
  const float* bl   = (const float*)d_in[5];
  const float* Wp   = (const float*)d_in[6];
  const float* bp   = (const float*)d_in[7];
  const float* Wd1  = (const float*)d_in[8];
  const float* bd1  = (const float*)d_in[9];
  const float* Wd2  = (const float*)d_in[10];
  const float* bd2  = (const float*)d_in[11];
  const float* Wd3  = (const float*)d_in[12];
  const float* bd3  = (const float*)d_in[13];
  const float* Wgl  = (const float*)d_in[14];
  const float* bgl  = (const float*)d_in[15];
  const float* Wgp  = (const float*)d_in[16];
  const float* bgp  = (const float*)d_in[17];
  const float* Wqkv = (const float*)d_in[18];
  const float* bqkv = (const float*)d_in[19];
  const float* Wo   = (const float*)d_in[20];
  const float* bo   = (const float*)d_in[21];
  const float* g_l  = (const float*)d_in[22];
  const float* be_l = (const float*)d_in[23];
  const float* g_p  = (const float*)d_in[24];
  const float* be_p = (const float*)d_in[25];

  float* ws  = (float*)d_ws;
  float* out = (float*)d_out;
  float* lig   = ws + LIG_OFF;
  float* poc   = ws + POC_OFF;
  float* lenh  = ws + LENH_OFF;
  float* penh  = ws + PENH_OFF;
  float* qkvl  = ws + QKVL_OFF;
  float* qkvp  = ws + QKVP_OFF;
  float* partL = ws + PARTL_OFF;
  float* partP = ws + PARTP_OFF;
  float* tab   = ws + TAB_OFF;

  prep_all<<<192, 256, 0, stream>>>(Wl, Wp, Wqkv, Wo, Wgl, Wgp, Wd1, bd1, Wd2, bd2, Wd3, bd3, ws);
  proj_kernel<<<192, 1024, 0, stream>>>(lf, pf, ws + WLT_OFF, bl, ws + WPT_OFF, bp, lig, poc);
  agg_gate_fused<<<NL/4 + NP/4, 1024, 0, stream>>>(lc, pc, tab, lig, poc,
                                                   ws + WGLT_OFF, bgl, ws + WGPT_OFF, bgp,
                                                   ws + WQT_OFF, bqkv,
                                                   lenh, penh, qkvl, qkvp);
  attn_part<<<512, 256, 0, stream>>>(qkvl, qkvp, partL, partP);
  merge_ln<<<192, 1024, 0, stream>>>(partL, partP, lenh, penh, ws + WOT_OFF, bo,
                                     g_l, be_l, g_p, be_p, out);
}

// Round 12
// 193.139 us; speedup vs baseline: 1.2704x; 1.0255x over previous
//
#include <hip/hip_runtime.h>
#include <math.h>

#define NL 512
#define NP 1024
#define HDIM 128

#define TAB_N 8192
#define DMAX 34.65f

// ---- workspace layout (float offsets) ----
#define M_OFF    128
#define WLT_OFF  (M_OFF)                      // WlT  [128][128]
#define WPT_OFF  (M_OFF + 16384)              // WpT  [128][128]
#define WQT_OFF  (M_OFF + 32768)              // WqkvT[128][384]
#define WOT_OFF  (M_OFF + 81920)              // WoT  [128][128]
#define WGLT_OFF (M_OFF + 98304)              // WglT [256][128]
#define WGPT_OFF (M_OFF + 131072)             // WgpT [256][128]
#define TAB_OFF  (M_OFF + 163840)             // m(d) table
#define LIG_OFF  (M_OFF + NL*NP)              // lig proj 512x128
#define POC_OFF  (LIG_OFF + NL*HDIM)          // poc proj 1024x128
#define LENH_OFF (POC_OFF + NP*HDIM)          // lig_enh 512x128
#define PENH_OFF (LENH_OFF + NL*HDIM)         // poc_enh 1024x128
#define QKVL_OFF (PENH_OFF + NP*HDIM)         // qkv for lig_enh 512x384
#define QKVP_OFF (QKVL_OFF + NL*384)          // qkv for poc_enh 1024x384
#define PARTL_OFF (QKVP_OFF + NP*384)         // lig partials: [512][8 h][8 slices][18]
#define PARTP_OFF (PARTL_OFF + 512*8*8*18)    // poc partials: [1024][8 h][4 slices][18]

__device__ __forceinline__ float dot4f(float4 a, float4 b){
  return fmaf(a.x,b.x, fmaf(a.y,b.y, fmaf(a.z,b.z, a.w*b.w)));
}

// ---------------- prep: transpose all matvec weights + build m(d) LUT (one kernel) ----------------
__device__ __forceinline__ void tpose(const float* __restrict__ src, float* __restrict__ dst,
                                      int O, int K, int blk0, int t){
  int e0 = blk0*1024 + t*4;
  #pragma unroll
  for (int i = 0; i < 4; i++){
    int e = e0 + i;
    int o = e / K, k = e - o*K;
    dst[(size_t)k*O + o] = src[(size_t)o*K + k];
  }
}
__global__ __launch_bounds__(256) void prep_all(const float* __restrict__ Wl, const float* __restrict__ Wp,
                                                const float* __restrict__ Wqkv, const float* __restrict__ Wo,
                                                const float* __restrict__ Wgl, const float* __restrict__ Wgp,
                                                const float* __restrict__ Wd1, const float* __restrict__ bd1,
                                                const float* __restrict__ Wd2, const float* __restrict__ bd2,
                                                const float* __restrict__ Wd3, const float* __restrict__ bd3,
                                                float* __restrict__ ws){
  int b = blockIdx.x, t = threadIdx.x;
  if (b < 160){
    if      (b < 16)  tpose(Wl,   ws + WLT_OFF,  128, 128, b,       t);
    else if (b < 32)  tpose(Wp,   ws + WPT_OFF,  128, 128, b - 16,  t);
    else if (b < 80)  tpose(Wqkv, ws + WQT_OFF,  384, 128, b - 32,  t);
    else if (b < 96)  tpose(Wo,   ws + WOT_OFF,  128, 128, b - 80,  t);
    else if (b < 128) tpose(Wgl,  ws + WGLT_OFF, 128, 256, b - 96,  t);
    else              tpose(Wgp,  ws + WGPT_OFF, 128, 256, b - 128, t);
    return;
  }
  // table part: blocks 160..191
  float* tab = ws + TAB_OFF;
  __shared__ float sWd1[32], sbd1[32], sWd2[2048], sbd2[64], swd3m[64];
  __shared__ float sbd3m;
  int idx = (b - 160) * 256 + t;
  if (t < 64){
    float s = 0.f;
    #pragma unroll 8
    for (int i = 0; i < 128; i++) s += Wd3[i*64 + t];
    swd3m[t] = s * (1.f/128.f);
  } else if (t == 64){
    float s = 0.f;
    for (int i = 0; i < 128; i++) s += bd3[i];
    sbd3m = s * (1.f/128.f);
  } else if (t >= 128 && t < 160){ sWd1[t-128] = Wd1[t-128]; sbd1[t-128] = bd1[t-128]; }
  else if (t >= 160 && t < 224){ sbd2[t-160] = bd2[t-160]; }
  for (int k = t; k < 2048; k += 256) sWd2[k] = Wd2[k];
  __syncthreads();

  float d = (float)idx * (DMAX / (float)(TAB_N - 1));
  float4 e1q[8];
  const float4* w1q = (const float4*)sWd1;
  const float4* b1q = (const float4*)sbd1;
  #pragma unroll
  for (int k4 = 0; k4 < 8; k4++){
    float4 w = w1q[k4], bb = b1q[k4];
    float4 e;
    e.x = fmaxf(fmaf(d, w.x, bb.x), 0.f);
    e.y = fmaxf(fmaf(d, w.y, bb.y), 0.f);
    e.z = fmaxf(fmaf(d, w.z, bb.z), 0.f);
    e.w = fmaxf(fmaf(d, w.w, bb.w), 0.f);
    e1q[k4] = e;
  }
  float mv = sbd3m;
  #pragma unroll 4
  for (int j2 = 0; j2 < 64; j2++){
    const float4* wrow = (const float4*)(sWd2 + j2*32);
    float a0 = 0.f, a1 = 0.f, a2 = 0.f, a3 = 0.f;
    #pragma unroll
    for (int k4 = 0; k4 < 8; k4++){
      float4 w = wrow[k4], e = e1q[k4];
      a0 = fmaf(w.x, e.x, a0);
      a1 = fmaf(w.y, e.y, a1);
      a2 = fmaf(w.z, e.z, a2);
      a3 = fmaf(w.w, e.w, a3);
    }
    float e2v = fmaxf(sbd2[j2] + ((a0+a1)+(a2+a3)), 0.f);
    mv = fmaf(swd3m[j2], e2v, mv);
  }
  tab[idx] = mv;
}

// ---------------- proj: 2 rows/block, 256 threads, 768 blocks (k-major weights) ----------------
__global__ __launch_bounds__(256) void proj_kernel(const float* __restrict__ lf, const float* __restrict__ pf,
                                                   const float* __restrict__ WlT, const float* __restrict__ bl,
                                                   const float* __restrict__ WpT, const float* __restrict__ bp,
                                                   float* __restrict__ lig, float* __restrict__ poc){
  int b = blockIdx.x, t = threadIdx.x;
  bool isLig = (b < NL/2);
  int r0 = isLig ? b*2 : (b - NL/2)*2;
  const float* in = (isLig ? lf : pf) + (size_t)r0*HDIM;
  const float* WT = isLig ? WlT : WpT;
  const float* bias = isLig ? bl : bp;
  float* out = (isLig ? lig : poc) + (size_t)r0*HDIM;
  __shared__ float sx[2*HDIM];
  sx[t] = in[t];
  __syncthreads();
  int r = t >> 7, col = t & 127;
  const float* xr = sx + r*HDIM;
  float acc = bias[col];
  #pragma unroll 8
  for (int k = 0; k < 128; k++) acc = fmaf(WT[k*128 + col], xr[k], acc);
  out[r*HDIM + col] = acc;
}

// ---------------- fused agg+gate+QKV, 2 rows/block, 512 threads, 768 blocks ----------------
__global__ __launch_bounds__(512) void agg_gate_fused(const float* __restrict__ lc, const float* __restrict__ pc,
                                                      const float* __restrict__ tab,
                                                      const float* __restrict__ lig, const float* __restrict__ poc,
                                                      const float* __restrict__ WglT, const float* __restrict__ bgl,
                                                      const float* __restrict__ WgpT, const float* __restrict__ bgp,
                                                      const float* __restrict__ WqkvT, const float* __restrict__ bqkv,
                                                      float* __restrict__ lenh, float* __restrict__ penh,
                                                      float* __restrict__ qkvl, float* __restrict__ qkvp){
  int b = blockIdx.x, t = threadIdx.x;
  bool isLig = (b < NL/2);
  int r0 = isLig ? b*2 : (b - NL/2)*2;
  int n = isLig ? NP : NL;
  const float* myFeat = isLig ? lig : poc;
  const float* otherFeat = isLig ? poc : lig;
  const float* myC = isLig ? lc : pc;
  const float* otC = isLig ? pc : lc;

  __shared__ float w[2*NP];          // 8 KB
  __shared__ float sx[2*HDIM];       // 1 KB
  __shared__ float sa[2*HDIM];       // 1 KB
  __shared__ float4 part4[8*64];     // 8 KB: [jg(8)][r(2)][c4(32)]
  __shared__ float gpart[512];       // 2 KB
  __shared__ float redm[8];
  __shared__ float sgm[2], sinv[2];

  int rr = t >> 8, u = t & 255;      // row-in-block, partner lane
  int lane = t & 63, wv = t >> 6;    // 8 waves
  int row = r0 + rr;

  if (t < 256) sx[t] = myFeat[(size_t)r0*HDIM + t];

  float cx = myC[row*3+0], cy = myC[row*3+1], cz = myC[row*3+2];
  const float inv_h = (float)(TAB_N - 1) / DMAX;
  int per = n >> 8;                  // 4 (lig) or 2 (poc)

  // ---- Phase A: softmax over partners, per row (4 waves per row) ----
  float xs[4];
  float lmax = -1e30f;
  for (int k = 0; k < per; k++){
    int j = u + (k << 8);
    float ox = otC[j*3+0], oy = otC[j*3+1], oz = otC[j*3+2];
    float dx = cx-ox, dy = cy-oy, dz = cz-oz;
    float d = sqrtf(fmaf(dx,dx, fmaf(dy,dy, dz*dz)));
    float xf = d * inv_h;
    int i0 = (int)xf;
    i0 = (i0 > TAB_N-2) ? (TAB_N-2) : i0;
    float f = xf - (float)i0;
    float v0 = tab[i0], v1 = tab[i0+1];
    xs[k] = -fmaf(f, v1 - v0, v0);
    lmax = fmaxf(lmax, xs[k]);
  }
  float v = lmax;
  #pragma unroll
  for (int off = 32; off; off >>= 1) v = fmaxf(v, __shfl_down(v, off));
  if (lane == 0) redm[wv] = v;
  __syncthreads();
  if (t < 2) sgm[t] = fmaxf(fmaxf(redm[t*4+0], redm[t*4+1]), fmaxf(redm[t*4+2], redm[t*4+3]));
  __syncthreads();
  float gm = sgm[rr];
  float lsum = 0.f;
  for (int k = 0; k < per; k++){
    float e = __expf(xs[k] - gm);
    w[rr*NP + u + (k << 8)] = e;
    lsum += e;
  }
  v = lsum;
  #pragma unroll
  for (int off = 32; off; off >>= 1) v += __shfl_down(v, off);
  if (lane == 0) redm[wv] = v;
  __syncthreads();
  if (t < 2) sinv[t] = 1.0f / ((redm[t*4+0] + redm[t*4+1]) + (redm[t*4+2] + redm[t*4+3]));
  __syncthreads();

  // ---- Phase B: aggregation, 8 j-groups x 2 rows x 32 float4 cols ----
  {
    int jg = t >> 6;                 // 8 groups
    int r  = (t >> 5) & 1;           // row
    int c4 = t & 31;                 // float4 column
    int per2 = n >> 3;               // 128 (lig) / 64 (poc)
    int jb0 = jg * per2;
    const float4* of4 = (const float4*)otherFeat;
    const float* wR = w + r*NP;
    float4 acc = {0,0,0,0};
    #pragma unroll 4
    for (int jj = 0; jj < per2; jj++){
      int j = jb0 + jj;
      float4 f = of4[(size_t)j*32 + c4];
      float ww = wR[j];
      acc.x = fmaf(ww, f.x, acc.x); acc.y = fmaf(ww, f.y, acc.y);
      acc.z = fmaf(ww, f.z, acc.z); acc.w = fmaf(ww, f.w, acc.w);
    }
    part4[(jg*2 + r)*32 + c4] = acc;
  }
  __syncthreads();
  #pragma unroll
  for (int s = 4; s >= 1; s >>= 1){
    if (t < s*64){
      int g2 = t >> 6, rem = t & 63;
      float4 a = part4[g2*64 + rem], bb = part4[(g2+s)*64 + rem];
      a.x += bb.x; a.y += bb.y; a.z += bb.z; a.w += bb.w;
      part4[g2*64 + rem] = a;
    }
    __syncthreads();
  }
  if (t < 256) sa[t] = ((const float*)part4)[t] * sinv[t >> 7];
  __syncthreads();

  // ---- Phase C: gate, all 512 threads: 2 rows x 128 cols x 2 k-halves ----
  {
    int r  = t >> 8;
    int kg = (t >> 7) & 1;
    int col = t & 127;
    const float* WT = isLig ? WglT : WgpT;   // [256][128]
    const float* inq = (kg == 0) ? (sx + r*HDIM) : (sa + r*HDIM);
    const float* wbase = WT + (size_t)kg*128*128;
    float g = 0.f;
    #pragma unroll 8
    for (int k = 0; k < 128; k++) g = fmaf(wbase[k*128 + col], inq[k], g);
    gpart[kg*256 + r*128 + col] = g;
  }
  __syncthreads();
  float enh_val = 0.f;
  if (t < 256){
    int r = t >> 7, col = t & 127;
    const float* bg = isLig ? bgl : bgp;
    float g = bg[col] + gpart[t] + gpart[256 + t];
    g = 1.0f / (1.0f + __expf(-g));
    float xv = sx[t], av = sa[t];
    enh_val = fmaf(g, xv - av, av);   // g*x + (1-g)*a
    float* dst = isLig ? (lenh + (size_t)(r0+r)*HDIM) : (penh + (size_t)(r0+r)*HDIM);
    dst[col] = enh_val;
  }
  __syncthreads();                    // all reads of sa done
  if (t < 256) sa[t] = enh_val;       // publish enh rows
  __syncthreads();

  // ---- Phase D: QKV projection, all 512 threads: 2 rows x 256 lanes ----
  {
    int r = t >> 8, ln = t & 255;
    const float* er = sa + r*HDIM;
    float* qout = (isLig ? qkvl : qkvp) + (size_t)(r0+r)*384;
    if (ln < 128){
      float a0 = bqkv[ln], a2 = bqkv[ln+256];
      #pragma unroll 4
      for (int k = 0; k < 128; k++){
        float xv = er[k];
        const float* wk = WqkvT + k*384;
        a0 = fmaf(wk[ln],     xv, a0);
        a2 = fmaf(wk[ln+256], xv, a2);
      }
      qout[ln] = a0; qout[ln+256] = a2;
    } else {
      float a1 = bqkv[ln];
      #pragma unroll 4
      for (int k = 0; k < 128; k++) a1 = fmaf(WqkvT[k*384 + ln], er[k], a1);
      qout[ln] = a1;
    }
  }
}

// ---------------- flash attention: 2 queries/thread, 4 split-k groups, 8-key tiles ----------------
__global__ __launch_bounds__(256) void attn_part(const float* __restrict__ qkvl, const float* __restrict__ qkvp,
                                                 float* __restrict__ partL, float* __restrict__ partP){
  int bx = blockIdx.x;
  int t = threadIdx.x;
  const float* qsrc; const float* kvsrc; int qt, slice; bool isLig;
  if (bx < 256){ isLig = true;  qt = bx >> 3; slice = bx & 7; qsrc = qkvl; kvsrc = qkvp; }
  else { int b2 = bx - 256; isLig = false; qt = b2 >> 2; slice = b2 & 3; qsrc = qkvp; kvsrc = qkvl; }
  int g = t >> 6, tt = t & 63;
  int h = tt >> 3, qp = tt & 7;
  int j0 = slice*128 + g*32;

  const float4* qA = (const float4*)(qsrc + (size_t)(qt*16+qp)*384 + h*16);
  const float4* qB = (const float4*)(qsrc + (size_t)(qt*16+qp+8)*384 + h*16);
  float4 a0 = qA[0], a1 = qA[1], a2 = qA[2], a3 = qA[3];
  float4 b0 = qB[0], b1 = qB[1], b2 = qB[2], b3 = qB[3];
  float mA = -1e30f, lA = 0.f, mB = -1e30f, lB = 0.f;
  float4 OA0={0,0,0,0}, OA1={0,0,0,0}, OA2={0,0,0,0}, OA3={0,0,0,0};
  float4 OB0={0,0,0,0}, OB1={0,0,0,0}, OB2={0,0,0,0}, OB3={0,0,0,0};

  __shared__ float sKV[8192];          // 4 groups x 8 keys x 256 floats = 32 KB
  float* myKV = sKV + g*2048;

  for (int tile = 0; tile < 4; tile++){
    int jbase = j0 + tile*8;
    __syncthreads();
    #pragma unroll
    for (int nn = 0; nn < 8; nn++){
      int v4 = tt + nn*64;             // 512 float4 per group
      int jj = v4 >> 6, c4 = v4 & 63;
      ((float4*)myKV)[jj*64 + c4] = *(const float4*)(kvsrc + (size_t)(jbase+jj)*384 + 128 + c4*4);
    }
    __syncthreads();
    float sA[8], sB[8];
    #pragma unroll
    for (int jj = 0; jj < 8; jj++){
      const float4* kk = (const float4*)(myKV + jj*256 + h*16);
      float4 k0 = kk[0], k1 = kk[1], k2 = kk[2], k3 = kk[3];
      sA[jj] = (dot4f(a0,k0) + dot4f(a1,k1) + dot4f(a2,k2) + dot4f(a3,k3)) * 0.25f;
      sB[jj] = (dot4f(b0,k0) + dot4f(b1,k1) + dot4f(b2,k2) + dot4f(b3,k3)) * 0.25f;
    }
    float mtA = sA[0], mtB = sB[0];
    #pragma unroll
    for (int jj = 1; jj < 8; jj++){ mtA = fmaxf(mtA, sA[jj]); mtB = fmaxf(mtB, sB[jj]); }
    float mnA = fmaxf(mA, mtA), mnB = fmaxf(mB, mtB);
    float cA = __expf(mA - mnA), cB = __expf(mB - mnB);
    lA *= cA; lB *= cB;
    OA0.x*=cA; OA0.y*=cA; OA0.z*=cA; OA0.w*=cA;
    OA1.x*=cA; OA1.y*=cA; OA1.z*=cA; OA1.w*=cA;
    OA2.x*=cA; OA2.y*=cA; OA2.z*=cA; OA2.w*=cA;
    OA3.x*=cA; OA3.y*=cA; OA3.z*=cA; OA3.w*=cA;
    OB0.x*=cB; OB0.y*=cB; OB0.z*=cB; OB0.w*=cB;
    OB1.x*=cB; OB1.y*=cB; OB1.z*=cB; OB1.w*=cB;
    OB2.x*=cB; OB2.y*=cB; OB2.z*=cB; OB2.w*=cB;
    OB3.x*=cB; OB3.y*=cB; OB3.z*=cB; OB3.w*=cB;
    #pragma unroll
    for (int jj = 0; jj < 8; jj++){
      float pA = __expf(sA[jj] - mnA);
      float pB = __expf(sB[jj] - mnB);
      lA += pA; lB += pB;
      const float4* vv = (const float4*)(myKV + jj*256 + 128 + h*16);
      float4 v0 = vv[0], v1 = vv[1], v2 = vv[2], v3 = vv[3];
      OA0.x = fmaf(pA, v0.x, OA0.x); OA0.y = fmaf(pA, v0.y, OA0.y);
      OA0.z = fmaf(pA, v0.z, OA0.z); OA0.w = fmaf(pA, v0.w, OA0.w);
      OA1.x = fmaf(pA, v1.x, OA1.x); OA1.y = fmaf(pA, v1.y, OA1.y);
      OA1.z = fmaf(pA, v1.z, OA1.z); OA1.w = fmaf(pA, v1.w, OA1.w);
      OA2.x = fmaf(pA, v2.x, OA2.x); OA2.y = fmaf(pA, v2.y, OA2.y);
      OA2.z = fmaf(pA, v2.z, OA2.z); OA2.w = fmaf(pA, v2.w, OA2.w);
      OA3.x = fmaf(pA, v3.x, OA3.x); OA3.y = fmaf(pA, v3.y, OA3.y);
      OA3.z = fmaf(pA, v3.z, OA3.z); OA3.w = fmaf(pA, v3.w, OA3.w);
      OB0.x = fmaf(pB, v0.x, OB0.x); OB0.y = fmaf(pB, v0.y, OB0.y);
      OB0.z = fmaf(pB, v0.z, OB0.z); OB0.w = fmaf(pB, v0.w, OB0.w);
      OB1.x = fmaf(pB, v1.x, OB1.x); OB1.y = fmaf(pB, v1.y, OB1.y);
      OB1.z = fmaf(pB, v1.z, OB1.z); OB1.w = fmaf(pB, v1.w, OB1.w);
      OB2.x = fmaf(pB, v2.x, OB2.x); OB2.y = fmaf(pB, v2.y, OB2.y);
      OB2.z = fmaf(pB, v2.z, OB2.z); OB2.w = fmaf(pB, v2.w, OB2.w);
      OB3.x = fmaf(pB, v3.x, OB3.x); OB3.y = fmaf(pB, v3.y, OB3.y);
      OB3.z = fmaf(pB, v3.z, OB3.z); OB3.w = fmaf(pB, v3.w, OB3.w);
    }
    mA = mnA; mB = mnB;
  }

  // ---- merge the 4 split-k groups via LDS (groups 1..3 publish; group 0 merges) ----
  __syncthreads();
  if (g > 0){
    float* bA = sKV + (size_t)((g-1)*128 + tt*2)*19;
    bA[0]=mA; bA[1]=lA;
    bA[2]=OA0.x; bA[3]=OA0.y; bA[4]=OA0.z; bA[5]=OA0.w;
    bA[6]=OA1.x; bA[7]=OA1.y; bA[8]=OA1.z; bA[9]=OA1.w;
    bA[10]=OA2.x; bA[11]=OA2.y; bA[12]=OA2.z; bA[13]=OA2.w;
    bA[14]=OA3.x; bA[15]=OA3.y; bA[16]=OA3.z; bA[17]=OA3.w;
    float* bB = bA + 19;
    bB[0]=mB; bB[1]=lB;
    bB[2]=OB0.x; bB[3]=OB0.y; bB[4]=OB0.z; bB[5]=OB0.w;
    bB[6]=OB1.x; bB[7]=OB1.y; bB[8]=OB1.z; bB[9]=OB1.w;
    bB[10]=OB2.x; bB[11]=OB2.y; bB[12]=OB2.z; bB[13]=OB2.w;
    bB[14]=OB3.x; bB[15]=OB3.y; bB[16]=OB3.z; bB[17]=OB3.w;
  }
  __syncthreads();
  if (g == 0){
    float M = mA, L = lA;
    float O[16] = {OA0.x,OA0.y,OA0.z,OA0.w, OA1.x,OA1.y,OA1.z,OA1.w,
                   OA2.x,OA2.y,OA2.z,OA2.w, OA3.x,OA3.y,OA3.z,OA3.w};
    #pragma unroll
    for (int gg = 1; gg < 4; gg++){
      const float* br = sKV + (size_t)((gg-1)*128 + tt*2)*19;
      float m1 = br[0], l1 = br[1];
      float Mn = fmaxf(M, m1);
      float e0 = __expf(M - Mn), e1 = __expf(m1 - Mn);
      L = L*e0 + l1*e1;
      #pragma unroll
      for (int k = 0; k < 16; k++) O[k] = O[k]*e0 + br[2+k]*e1;
      M = Mn;
    }
    int rowA = qt*16 + qp;
    float* dst = isLig ? (partL + ((size_t)(rowA*8 + h)*8 + slice)*18)
                       : (partP + ((size_t)(rowA*8 + h)*4 + slice)*18);
    dst[0] = M; dst[1] = L;
    #pragma unroll
    for (int k = 0; k < 16; k++) dst[2+k] = O[k];
    M = mB; L = lB;
    float Ob[16] = {OB0.x,OB0.y,OB0.z,OB0.w, OB1.x,OB1.y,OB1.z,OB1.w,
                    OB2.x,OB2.y,OB2.z,OB2.w, OB3.x,OB3.y,OB3.z,OB3.w};
    #pragma unroll
    for (int gg = 1; gg < 4; gg++){
      const float* br = sKV + (size_t)((gg-1)*128 + tt*2 + 1)*19;
      float m1 = br[0], l1 = br[1];
      float Mn = fmaxf(M, m1);
      float e0 = __expf(M - Mn), e1 = __expf(m1 - Mn);
      L = L*e0 + l1*e1;
      #pragma unroll
      for (int k = 0; k < 16; k++) Ob[k] = Ob[k]*e0 + br[2+k]*e1;
      M = Mn;
    }
    int rowB = qt*16 + qp + 8;
    float* dstB = isLig ? (partL + ((size_t)(rowB*8 + h)*8 + slice)*18)
                        : (partP + ((size_t)(rowB*8 + h)*4 + slice)*18);
    dstB[0] = M; dstB[1] = L;
    #pragma unroll
    for (int k = 0; k < 16; k++) dstB[2+k] = Ob[k];
  }
}

// ---------------- merge partials + Wo proj (k-major) + residual + LayerNorm; 2 rows/block ----------------
__global__ __launch_bounds__(256) void merge_ln(const float* __restrict__ partL, const float* __restrict__ partP,
                                                const float* __restrict__ lenh, const float* __restrict__ penh,
                                                const float* __restrict__ WoT, const float* __restrict__ bo,
                                                const float* __restrict__ g_l, const float* __restrict__ be_l,
                                                const float* __restrict__ g_p, const float* __restrict__ be_p,
                                                float* __restrict__ out){
  int b = blockIdx.x, t = threadIdx.x;      // 768 blocks
  int r0 = b*2;
  int r = t >> 7, c = t & 127;
  int gr = r0 + r;
  int h = c >> 4, cc = c & 15;
  int ns; const float* base;
  if (gr < NL){ ns = 8; base = partL + ((size_t)(gr*8 + h))*8*18; }
  else        { ns = 4; base = partP + ((size_t)((gr-NL)*8 + h))*4*18; }
  float M = -1e30f;
  for (int s = 0; s < ns; s++) M = fmaxf(M, base[s*18]);
  float Lsum = 0.f, Osum = 0.f;
  for (int s = 0; s < ns; s++){
    float e = __expf(base[s*18] - M);
    Lsum = fmaf(e, base[s*18+1], Lsum);
    Osum = fmaf(e, base[s*18+2+cc], Osum);
  }
  __shared__ float sAtt[2*HDIM];
  sAtt[t] = Osum / Lsum;
  __syncthreads();
  float o = bo[c];
  const float* sA = sAtt + r*HDIM;
  #pragma unroll 8
  for (int k = 0; k < 128; k++) o = fmaf(WoT[k*128 + c], sA[k], o);
  const float* enh = (gr < NL) ? (lenh + (size_t)gr*HDIM) : (penh + (size_t)(gr-NL)*HDIM);
  float x = enh[c] + o;
  __shared__ float sred[8];
  int wid = t >> 6;
  float v = x;
  #pragma unroll
  for (int off = 32; off; off >>= 1) v += __shfl_down(v, off);
  if ((t & 63) == 0) sred[wid] = v;
  __syncthreads();
  float mu = (sred[2*r] + sred[2*r+1]) * (1.f/128.f);
  float dx = x - mu;
  v = dx*dx;
  #pragma unroll
  for (int off = 32; off; off >>= 1) v += __shfl_down(v, off);
  if ((t & 63) == 0) sred[4 + wid] = v;
  __syncthreads();
  float var = (sred[4 + 2*r] + sred[4 + 2*r+1]) * (1.f/128.f);
  float y = dx * rsqrtf(var + 1e-5f);
  if (gr < NL) y = fmaf(y, g_l[c], be_l[c]);
  else         y = fmaf(y, g_p[c], be_p[c]);
  out[(size_t)gr*HDIM + c] = y;
}

extern "C" void kernel_launch(void* const* d_in, const int* in_sizes, int n_in,
                              void* d_out, int out_size, void* d_ws, size_t ws_size,
                              hipStream_t stream){
  const float* lf   = (const float*)d_in[0];
  const float* pf   = (const float*)d_in[1];
  const float* lc   = (const float*)d_in[2];
  const float* pc   = (const float*)d_in[3];
  const float* Wl   = (const float*)d_in[4];
  const float* bl   = (const float*)d_in[5];
  const float* Wp   = (const float*)d_in[6];
  const float* bp   = (const float*)d_in[7];
  const float* Wd1  = (const float*)d_in[8];
  const float* bd1  = (const float*)d_in[9];
  const float* Wd2  = (const float*)d_in[10];
  const float* bd2  = (const float*)d_in[11];
  const float* Wd3  = (const float*)d_in[12];
  const float* bd3  = (const float*)d_in[13];
  const float* Wgl  = (const float*)d_in[14];
  const float* bgl  = (const float*)d_in[15];
  const float* Wgp  = (const float*)d_in[16];
  const float* bgp  = (const float*)d_in[17];
  const float* Wqkv = (const float*)d_in[18];
  const float* bqkv = (const float*)d_in[19];
  const float* Wo   = (const float*)d_in[20];
  const float* bo   = (const float*)d_in[21];
  const float* g_l  = (const float*)d_in[22];
  const float* be_l = (const float*)d_in[23];
  const float* g_p  = (const float*)d_in[24];
  const float* be_p = (const float*)d_in[25];

  float* ws  = (float*)d_ws;
  float* out = (float*)d_out;
  float* lig   = ws + LIG_OFF;
  float* poc   = ws + POC_OFF;
  float* lenh  = ws + LENH_OFF;
  float* penh  = ws + PENH_OFF;
  float* qkvl  = ws + QKVL_OFF;
  float* qkvp  = ws + QKVP_OFF;
  float* partL = ws + PARTL_OFF;
  float* partP = ws + PARTP_OFF;
  float* tab   = ws + TAB_OFF;

  prep_all<<<192, 256, 0, stream>>>(Wl, Wp, Wqkv, Wo, Wgl, Wgp, Wd1, bd1, Wd2, bd2, Wd3, bd3, ws);
  proj_kernel<<<NL/2 + NP/2, 256, 0, stream>>>(lf, pf, ws + WLT_OFF, bl, ws + WPT_OFF, bp, lig, poc);
  agg_gate_fused<<<NL/2 + NP/2, 512, 0, stream>>>(lc, pc, tab, lig, poc,
                                                  ws + WGLT_OFF, bgl, ws + WGPT_OFF, bgp,
                                                  ws + WQT_OFF, bqkv,
                                                  lenh, penh, qkvl, qkvp);
  attn_part<<<512, 256, 0, stream>>>(qkvl, qkvp, partL, partP);
  merge_ln<<<NL/2 + NP/2, 256, 0, stream>>>(partL, partP, lenh, penh, ws + WOT_OFF, bo,
                                            g_l, be_l, g_p, be_p, out);
}